// Round 2
// baseline (16314.879 us; speedup 1.0000x reference)
//
#include <hip/hip_runtime.h>
#include <math.h>

#define BB 8
#define TT 1024
#define DM 512
#define ROWS (BB*TT)     // 8192
#define ROWS1 (BB*(TT-1))// 8184
#define GRU_J 8          // hidden dims per block
#define GRU_GPB 64       // blocks per batch
#define GRU_BLK (BB*GRU_GPB)  // 512 blocks

__device__ __forceinline__ float sigm_(float v){ return 1.f/(1.f+expf(-v)); }

// ---------------- elementwise ----------------
__global__ __launch_bounds__(256) void delta_kernel(const float* __restrict__ x,
    const float* __restrict__ ts, float* __restrict__ delta)
{
  size_t i = (size_t)blockIdx.x*256 + threadIdx.x;
  int d = (int)(i & (DM-1));
  int r = (int)(i >> 9);
  int b = r / (TT-1), ii = r % (TT-1);
  float dt = ts[b*TT+ii+1] - ts[b*TT+ii];
  float x1 = x[((size_t)b*TT+ii+1)*DM + d];
  float x0 = x[((size_t)b*TT+ii)*DM + d];
  delta[i] = (x1 - x0) / dt;
}

template<int INIT, int WRITE_Y>
__global__ __launch_bounds__(256) void rk_kernel(float* __restrict__ acc,
    float* y, const float* __restrict__ delta,
    const float* __restrict__ f, const float* __restrict__ ts,
    float wa, float cy)
{
  size_t i = (size_t)blockIdx.x*256 + threadIdx.x;
  int r = (int)(i >> 9);
  int b = r / (TT-1), ii = r % (TT-1);
  float fv = f[i];
  float a = INIT ? 0.f : acc[i];
  acc[i] = a + wa*fv;
  if (WRITE_Y) {
    float dt = ts[b*TT+ii+1] - ts[b*TT+ii];
    y[i] = delta[i] + cy*dt*fv;
  }
}

__global__ __launch_bounds__(256) void states_kernel(const float* __restrict__ x,
    const float* __restrict__ ts, const float* __restrict__ acc,
    float* __restrict__ hin)
{
  size_t i = (size_t)blockIdx.x*256 + threadIdx.x;
  int d = (int)(i & (DM-1));
  int r = (int)(i >> 9);
  int b = r >> 10, t = r & (TT-1);
  float v = 0.f;
  if (t > 0) {
    int ii = t-1;
    float dt = ts[b*TT+ii+1] - ts[b*TT+ii];
    v = x[((size_t)b*TT+ii)*DM + d] + dt*(1.f/6.f)*acc[((size_t)b*(TT-1)+ii)*DM + d];
  }
  hin[i] = v;
}

__global__ __launch_bounds__(256) void timeenc_kernel(const float* __restrict__ x,
    const float* __restrict__ ts, const float* __restrict__ te_a,
    const float* __restrict__ te_b, float* __restrict__ z)
{
  size_t i = (size_t)blockIdx.x*256 + threadIdx.x;
  int d = (int)(i & (DM-1));
  int r = (int)(i >> 9);
  float t = ts[r];
  float tm;
  if (d & 1) {
    int j = d >> 1;                       // odd channels: ramp
    tm = t*te_a[j] + te_b[j];
  } else {
    int fi = d >> 2;                      // even: interleaved sin/cos
    float fr = expf(-(float)fi * 0.061606661f) * 1.5707964f; // exp(-i*ln(2500)/127)*pi/2
    float ph = t * fr;
    tm = ((d & 3) == 0) ? sinf(ph) : cosf(ph);
  }
  z[i] = x[i] + tm;
}

// ---------------- LayerNorm (block per row, D=512) ----------------
__global__ __launch_bounds__(256) void ln_kernel(const float* __restrict__ x,
    const float* __restrict__ w, const float* __restrict__ b,
    float* __restrict__ out)
{
  int row = blockIdx.x;
  int tid = threadIdx.x;
  const float* xr = x + (size_t)row*DM;
  float2 v = *(const float2*)(xr + tid*2);
  float s = v.x+v.y, sq = v.x*v.x + v.y*v.y;
  #pragma unroll
  for (int off=1; off<64; off<<=1){ s += __shfl_xor(s,off); sq += __shfl_xor(sq,off); }
  __shared__ float rs[4], rq[4];
  int wid = tid>>6;
  if ((tid&63)==0){ rs[wid]=s; rq[wid]=sq; }
  __syncthreads();
  s = rs[0]+rs[1]+rs[2]+rs[3];
  sq = rq[0]+rq[1]+rq[2]+rq[3];
  float mean = s*(1.f/DM);
  float var = sq*(1.f/DM) - mean*mean;
  float inv = rsqrtf(var + 1e-5f);
  float2 wv = *(const float2*)(w + tid*2);
  float2 bv = *(const float2*)(b + tid*2);
  float2 o;
  o.x = (v.x-mean)*inv*wv.x + bv.x;
  o.y = (v.y-mean)*inv*wv.y + bv.y;
  *(float2*)(out + (size_t)row*DM + tid*2) = o;
}

// ---------------- GEMM: C[m][n] = act(dot(A[m,:],W[n,:]) + bias[n]) (+res) ----------------
template<int ACT>  // 0 none, 1 relu, 2 tanh
__global__ __launch_bounds__(256) void gemm_kernel(
    const float* __restrict__ A, const float* __restrict__ W,
    const float* __restrict__ bias, const float* res,
    float* C, int M, int N, int K, int ldc)
{
  __shared__ float As[16][132];   // [k][m]
  __shared__ float Ws[16][68];    // [k][n]
  const int bm = blockIdx.y * 128;
  const int bn = blockIdx.x * 64;
  const int tid = threadIdx.x;
  const int rg = tid >> 4;        // 0..15
  const int cg = tid & 15;        // 0..15
  float acc[8][4];
  #pragma unroll
  for (int i=0;i<8;i++){
    #pragma unroll
    for (int j=0;j<4;j++) acc[i][j]=0.f;
  }
  const int ar = tid >> 1;            // 0..127
  const int ak = (tid & 1) * 8;
  const int wr = tid >> 2;            // 0..63
  const int wk = (tid & 3) * 4;

  for (int k0 = 0; k0 < K; k0 += 16) {
    float4 a0 = {0,0,0,0}, a1 = {0,0,0,0};
    int gr = bm + ar;
    if (gr < M) {
      const float* p = A + (size_t)gr * K + k0 + ak;
      a0 = *(const float4*)p;
      a1 = *(const float4*)(p + 4);
    }
    As[ak+0][ar]=a0.x; As[ak+1][ar]=a0.y; As[ak+2][ar]=a0.z; As[ak+3][ar]=a0.w;
    As[ak+4][ar]=a1.x; As[ak+5][ar]=a1.y; As[ak+6][ar]=a1.z; As[ak+7][ar]=a1.w;
    {
      const float* p = W + (size_t)(bn + wr) * K + k0 + wk;
      float4 w4 = *(const float4*)p;
      Ws[wk+0][wr]=w4.x; Ws[wk+1][wr]=w4.y; Ws[wk+2][wr]=w4.z; Ws[wk+3][wr]=w4.w;
    }
    __syncthreads();
    #pragma unroll
    for (int kk=0;kk<16;kk++) {
      float4 av0 = *(const float4*)&As[kk][rg*8];
      float4 av1 = *(const float4*)&As[kk][rg*8+4];
      float4 wv  = *(const float4*)&Ws[kk][cg*4];
      float am[8] = {av0.x,av0.y,av0.z,av0.w,av1.x,av1.y,av1.z,av1.w};
      float wm[4] = {wv.x,wv.y,wv.z,wv.w};
      #pragma unroll
      for (int i=0;i<8;i++){
        #pragma unroll
        for (int j=0;j<4;j++) acc[i][j] = fmaf(am[i], wm[j], acc[i][j]);
      }
    }
    __syncthreads();
  }
  const int gn0 = bn + cg*4;
  float4 bv = *(const float4*)(bias + gn0);
  #pragma unroll
  for (int i=0;i<8;i++) {
    int gm = bm + rg*8 + i;
    if (gm >= M) continue;
    float4 v;
    v.x = acc[i][0]+bv.x; v.y = acc[i][1]+bv.y;
    v.z = acc[i][2]+bv.z; v.w = acc[i][3]+bv.w;
    if (ACT==1){ v.x=fmaxf(v.x,0.f); v.y=fmaxf(v.y,0.f); v.z=fmaxf(v.z,0.f); v.w=fmaxf(v.w,0.f); }
    if (ACT==2){ v.x=tanhf(v.x); v.y=tanhf(v.y); v.z=tanhf(v.z); v.w=tanhf(v.w); }
    if (res) {
      float4 r4 = *(const float4*)(res + (size_t)gm*ldc + gn0);
      v.x+=r4.x; v.y+=r4.y; v.z+=r4.z; v.w+=r4.w;
    }
    *(float4*)(C + (size_t)gm*ldc + gn0) = v;
  }
}

// ---------------- attention ----------------
template<int CAUSAL>
__global__ __launch_bounds__(256) void attn_kernel(const float* __restrict__ QKV,
                                                   float* __restrict__ O)
{
  __shared__ float qt[8][68];
  __shared__ float kt[32][68];
  __shared__ float vt[32][68];
  __shared__ float sc[8][1028];
  const int bh = blockIdx.x;
  const int b = bh >> 3, h = bh & 7;
  const int q0 = blockIdx.y * 8;
  const int tid = threadIdx.x;
  const int qrow = tid >> 5;       // 0..7
  const int klane = tid & 31;      // 0..31
  const float* base = QKV + (size_t)b*TT*1536;
  for (int idx = tid; idx < 8*64; idx += 256) {
    int q = idx >> 6, d = idx & 63;
    qt[q][d] = base[(size_t)(q0+q)*1536 + h*64 + d];
  }
  const int nkt = CAUSAL ? (q0/32 + 1) : (TT/32);
  for (int t0 = 0; t0 < nkt; t0++) {
    __syncthreads();
    for (int idx = tid; idx < 32*64; idx += 256) {
      int kk = idx >> 6, d = idx & 63;
      kt[kk][d] = base[(size_t)(t0*32+kk)*1536 + 512 + h*64 + d];
    }
    __syncthreads();
    float s = 0.f;
    #pragma unroll
    for (int d = 0; d < 64; d += 4) {
      float4 qv = *(const float4*)&qt[qrow][d];
      float4 kv = *(const float4*)&kt[klane][d];
      s += qv.x*kv.x + qv.y*kv.y + qv.z*kv.z + qv.w*kv.w;
    }
    int kg = t0*32 + klane;
    s *= 0.125f;
    if (CAUSAL && kg > q0 + qrow) s = -1e30f;
    sc[qrow][kg] = s;
  }
  __syncthreads();
  const int nk = nkt*32;
  float mx = -1e30f;
  for (int k = klane; k < nk; k += 32) mx = fmaxf(mx, sc[qrow][k]);
  #pragma unroll
  for (int off=1; off<32; off<<=1) mx = fmaxf(mx, __shfl_xor(mx, off));
  float sum = 0.f;
  for (int k = klane; k < nk; k += 32) { float e = expf(sc[qrow][k]-mx); sc[qrow][k]=e; sum += e; }
  #pragma unroll
  for (int off=1; off<32; off<<=1) sum += __shfl_xor(sum, off);
  float inv = 1.f/sum;
  for (int k = klane; k < nk; k += 32) sc[qrow][k] *= inv;
  float o0=0.f, o1=0.f;
  for (int t0 = 0; t0 < nkt; t0++) {
    __syncthreads();
    for (int idx = tid; idx < 32*64; idx += 256) {
      int kk = idx >> 6, d = idx & 63;
      vt[kk][d] = base[(size_t)(t0*32+kk)*1536 + 1024 + h*64 + d];
    }
    __syncthreads();
    #pragma unroll
    for (int kk=0; kk<32; kk++) {
      float p = sc[qrow][t0*32+kk];
      o0 += p*vt[kk][klane];
      o1 += p*vt[kk][klane+32];
    }
  }
  float* op = O + (size_t)(b*TT + q0 + qrow)*DM + h*64 + klane;
  op[0]  = o0;
  op[32] = o1;
}

// ---------------- GRU scan v2: per-batch pipelines ----------------
// 512 blocks = 8 batches x 64 slices of 8 hidden dims. Weights for the slice
// (3 gates x 8 x 512) live in LDS. Per step: poll per-batch flag array
// (RELAXED loads, one acquire fence), load h_b (2KB) agent-coherent, dot,
// shuffle-reduce, 8 threads finalize + release flag. No contended atomics,
// no per-poll cache invalidates.
__global__ __launch_bounds__(256) void gru_scan_kernel(
    const float* __restrict__ gx,   // (B*T,1536) includes bih
    const float* __restrict__ whh,  // (1536,512)
    const float* __restrict__ bhh,  // (1536)
    float* __restrict__ Hs,         // (B*T,512)
    float* hbuf,                    // 2 * B*512 ping-pong
    int* flags)                     // B*64 progress flags (memset 0)
{
  __shared__ float wlds[3*GRU_J*516];
  __shared__ float hsp[512];
  __shared__ float red[4][3][GRU_J];
  __shared__ float gxs[3][GRU_J];

  const int blk = blockIdx.x;
  const int b = blk >> 6;          // batch
  const int g = blk & 63;          // slice
  const int j0 = g * GRU_J;
  const int tid = threadIdx.x;
  const int lane = tid & 63;
  const int wv = tid >> 6;

  for (int idx = tid; idx < 3*GRU_J*512; idx += 256) {
    int gate = idx >> 12;          // /(8*512)
    int rem  = idx & 4095;
    int jj2  = rem >> 9, k = rem & 511;
    wlds[(gate*GRU_J+jj2)*516 + k] = whh[(size_t)(gate*512 + j0 + jj2)*512 + k];
  }
  float bh0=0.f, bh1=0.f, bh2=0.f;
  if (tid < GRU_J) {
    bh0 = bhh[j0+tid]; bh1 = bhh[512+j0+tid]; bh2 = bhh[1024+j0+tid];
  }
  const int jj = tid & (GRU_J-1);
  const int kc = tid >> 3;          // 0..31, K-chunk of 16
  const int k0 = kc*16;
  const float* w0p = &wlds[(0*GRU_J+jj)*516 + k0];
  const float* w1p = &wlds[(1*GRU_J+jj)*516 + k0];
  const float* w2p = &wlds[(2*GRU_J+jj)*516 + k0];
  __syncthreads();

  for (int t = 0; t < TT; t++) {
    // gx load issued before the poll so its latency hides under the wait
    float gxv = 0.f;
    if (tid < 3*GRU_J) {
      int gate = tid >> 3, j = tid & 7;
      gxv = gx[((size_t)b*TT + t)*1536 + gate*512 + j0 + j];
    }
    if (t > 0) {
      if (wv == 0) {
        for (;;) {
          int f = __hip_atomic_load(&flags[b*GRU_GPB + lane],
                                    __ATOMIC_RELAXED, __HIP_MEMORY_SCOPE_AGENT);
          if (__all(f >= t)) break;
          __builtin_amdgcn_s_sleep(1);
        }
        __builtin_amdgcn_fence(__ATOMIC_ACQUIRE, "agent");
      }
      __syncthreads();
      const float* src = hbuf + ((((t&1)^1)*BB + b) << 9);
      float h0 = __hip_atomic_load(src + tid,       __ATOMIC_RELAXED, __HIP_MEMORY_SCOPE_AGENT);
      float h1 = __hip_atomic_load(src + 256 + tid, __ATOMIC_RELAXED, __HIP_MEMORY_SCOPE_AGENT);
      hsp[tid] = h0; hsp[256+tid] = h1;
    } else {
      hsp[tid] = 0.f; hsp[256+tid] = 0.f;
    }
    if (tid < 3*GRU_J) gxs[tid>>3][tid&7] = gxv;
    __syncthreads();

    float s0=0.f, s1=0.f, s2=0.f;
    #pragma unroll
    for (int q = 0; q < 4; q++) {
      int qq = (((kc>>1) + q) & 3) * 4;   // rotate quarters: spread LDS banks
      float4 h4 = *(const float4*)&hsp[k0 + qq];
      float4 a = *(const float4*)(w0p + qq);
      float4 c = *(const float4*)(w1p + qq);
      float4 d = *(const float4*)(w2p + qq);
      s0 += a.x*h4.x + a.y*h4.y + a.z*h4.z + a.w*h4.w;
      s1 += c.x*h4.x + c.y*h4.y + c.z*h4.z + c.w*h4.w;
      s2 += d.x*h4.x + d.y*h4.y + d.z*h4.z + d.w*h4.w;
    }
    #pragma unroll
    for (int off = 8; off < 64; off <<= 1) {
      s0 += __shfl_xor(s0, off);
      s1 += __shfl_xor(s1, off);
      s2 += __shfl_xor(s2, off);
    }
    if (lane < GRU_J) {
      red[wv][0][lane] = s0; red[wv][1][lane] = s1; red[wv][2][lane] = s2;
    }
    __syncthreads();
    if (tid < GRU_J) {
      float sr = red[0][0][tid]+red[1][0][tid]+red[2][0][tid]+red[3][0][tid];
      float sz = red[0][1][tid]+red[1][1][tid]+red[2][1][tid]+red[3][1][tid];
      float sn = red[0][2][tid]+red[1][2][tid]+red[2][2][tid]+red[3][2][tid];
      float r  = sigm_(gxs[0][tid] + sr + bh0);
      float z  = sigm_(gxs[1][tid] + sz + bh1);
      float n  = tanhf(gxs[2][tid] + r*(sn + bh2));
      float hold = hsp[j0 + tid];
      float hnew = (1.f - z)*n + z*hold;
      Hs[((size_t)b*TT + t)*DM + j0 + tid] = hnew;
      __hip_atomic_store(&hbuf[(((t&1)*BB + b) << 9) + j0 + tid], hnew,
                         __ATOMIC_RELAXED, __HIP_MEMORY_SCOPE_AGENT);
    }
    __syncthreads();   // drains vmcnt for the h stores (compiler waitcnt before barrier)
    if (tid == 0)
      __hip_atomic_store(&flags[b*GRU_GPB + g], t+1,
                         __ATOMIC_RELEASE, __HIP_MEMORY_SCOPE_AGENT);
  }
}

// ---------------- host ----------------
static void launch_gemm(int act, const float* A, const float* W, const float* bias,
                        const float* res, float* C, int M, int N, int K, int ldc,
                        hipStream_t stream)
{
  dim3 grid(N/64, (M+127)/128), blk(256);
  switch(act){
    case 1: gemm_kernel<1><<<grid,blk,0,stream>>>(A,W,bias,res,C,M,N,K,ldc); break;
    case 2: gemm_kernel<2><<<grid,blk,0,stream>>>(A,W,bias,res,C,M,N,K,ldc); break;
    default: gemm_kernel<0><<<grid,blk,0,stream>>>(A,W,bias,res,C,M,N,K,ldc); break;
  }
}

extern "C" void kernel_launch(void* const* d_in, const int* in_sizes, int n_in,
                              void* d_out, int out_size, void* d_ws, size_t ws_size,
                              hipStream_t stream)
{
  (void)in_sizes; (void)n_in; (void)out_size; (void)ws_size;
  const float* x       = (const float*)d_in[0];
  const float* ts      = (const float*)d_in[1];
  const float* ode_w1  = (const float*)d_in[2];
  const float* ode_b1  = (const float*)d_in[3];
  const float* ode_w2  = (const float*)d_in[4];
  const float* ode_b2  = (const float*)d_in[5];
  const float* gru_wih = (const float*)d_in[6];
  const float* gru_whh = (const float*)d_in[7];
  const float* gru_bih = (const float*)d_in[8];
  const float* gru_bhh = (const float*)d_in[9];
  const float* te_a    = (const float*)d_in[10];
  const float* te_b    = (const float*)d_in[11];
  const float* t_in_w  = (const float*)d_in[12];
  const float* t_in_b  = (const float*)d_in[13];
  const float* t_out_w = (const float*)d_in[14];
  const float* t_out_b = (const float*)d_in[15];
  const float* t_ln1_w = (const float*)d_in[16];
  const float* t_ln1_b = (const float*)d_in[17];
  const float* t_ln2_w = (const float*)d_in[18];
  const float* t_ln2_b = (const float*)d_in[19];
  const float* t_ff1_w = (const float*)d_in[20];
  const float* t_ff1_b = (const float*)d_in[21];
  const float* t_ff2_w = (const float*)d_in[22];
  const float* t_ff2_b = (const float*)d_in[23];
  const float* t_lnf_w = (const float*)d_in[24];
  const float* t_lnf_b = (const float*)d_in[25];
  const float* ca_in_w = (const float*)d_in[26];
  const float* ca_in_b = (const float*)d_in[27];
  const float* ca_out_w= (const float*)d_in[28];
  const float* ca_out_b= (const float*)d_in[29];
  const float* ca_lin_w= (const float*)d_in[30];
  const float* ca_lin_b= (const float*)d_in[31];
  const float* ca_ln_w = (const float*)d_in[32];
  const float* ca_ln_b = (const float*)d_in[33];

  float* ws = (float*)d_ws;
  const size_t SZ = (size_t)ROWS * DM;      // 4M floats = 16MB
  float* deltab = ws + 0*SZ;                // ODE delta; later attn O
  float* ycur   = ws + 1*SZ;
  float* fcur   = ws + 2*SZ;                // later cross-attn pre-LN
  float* accb   = ws + 3*SZ;
  float* ff1    = ws + 0*SZ;                // aliases [0,4SZ) (ODE bufs dead by then)
  float* ybuf   = ws + 4*SZ;                // tanh tmp / LN y / cross AO
  float* hin    = ws + 5*SZ;                // H_in; later zf
  float* qkv    = ws + 6*SZ;                // 3*SZ: gx, later QKV
  float* hsb    = ws + 9*SZ;                // GRU output H (persists)
  float* zbuf   = ws + 10*SZ;               // transformer stream
  float* hbuf   = ws + 11*SZ;               // 2*B*512 GRU h ping-pong
  int*   flags  = (int*)(ws + 11*SZ + 2*BB*512);

  hipMemsetAsync(flags, 0, GRU_BLK*sizeof(int), stream);

  // ---- ODE (RK4 over parallel states) ----
  delta_kernel<<<ROWS1*DM/256, 256, 0, stream>>>(x, ts, deltab);
  const float* yin = deltab;
  const float was[4] = {1.f, 2.f, 2.f, 1.f};
  const float cys[4] = {0.5f, 0.5f, 1.f, 0.f};
  for (int s4 = 0; s4 < 4; s4++) {
    launch_gemm(2, yin, ode_w1, ode_b1, nullptr, ybuf, ROWS1, 512, 512, 512, stream);
    launch_gemm(0, ybuf, ode_w2, ode_b2, nullptr, fcur, ROWS1, 512, 512, 512, stream);
    if (s4 == 0)
      rk_kernel<1,1><<<ROWS1*DM/256,256,0,stream>>>(accb, ycur, deltab, fcur, ts, was[s4], cys[s4]);
    else if (s4 < 3)
      rk_kernel<0,1><<<ROWS1*DM/256,256,0,stream>>>(accb, ycur, deltab, fcur, ts, was[s4], cys[s4]);
    else
      rk_kernel<0,0><<<ROWS1*DM/256,256,0,stream>>>(accb, nullptr, deltab, fcur, ts, was[s4], 0.f);
    yin = ycur;
  }
  states_kernel<<<ROWS*DM/256,256,0,stream>>>(x, ts, accb, hin);

  // ---- GRU ----
  launch_gemm(0, hin, gru_wih, gru_bih, nullptr, qkv, ROWS, 1536, 512, 1536, stream);
  gru_scan_kernel<<<GRU_BLK, 256, 0, stream>>>(qkv, gru_whh, gru_bhh, hsb, hbuf, flags);

  // ---- time encoding ----
  timeenc_kernel<<<ROWS*DM/256,256,0,stream>>>(x, ts, te_a, te_b, zbuf);

  // ---- transformer (2 layers, pre-norm, causal) ----
  for (int l = 0; l < 2; l++) {
    ln_kernel<<<ROWS,256,0,stream>>>(zbuf, t_ln1_w + l*512, t_ln1_b + l*512, ybuf);
    launch_gemm(0, ybuf, t_in_w + (size_t)l*1536*512, t_in_b + l*1536, nullptr, qkv, ROWS, 1536, 512, 1536, stream);
    attn_kernel<1><<<dim3(64, TT/8), 256, 0, stream>>>(qkv, deltab);
    launch_gemm(0, deltab, t_out_w + (size_t)l*512*512, t_out_b + l*512, zbuf, zbuf, ROWS, 512, 512, 512, stream);
    ln_kernel<<<ROWS,256,0,stream>>>(zbuf, t_ln2_w + l*512, t_ln2_b + l*512, ybuf);
    launch_gemm(1, ybuf, t_ff1_w + (size_t)l*2048*512, t_ff1_b + l*2048, nullptr, ff1, ROWS, 2048, 512, 2048, stream);
    launch_gemm(0, ff1, t_ff2_w + (size_t)l*512*2048, t_ff2_b + l*512, zbuf, zbuf, ROWS, 512, 2048, 512, stream);
  }
  ln_kernel<<<ROWS,256,0,stream>>>(zbuf, t_lnf_w, t_lnf_b, hin);   // hin = zf now

  // ---- cross attention: Q from Hs, K/V from zf ----
  launch_gemm(0, hsb, ca_in_w,            ca_in_b,       nullptr, qkv,       ROWS,  512, 512, 1536, stream);
  launch_gemm(0, hin, ca_in_w + 512*512,  ca_in_b + 512, nullptr, qkv + 512, ROWS, 1024, 512, 1536, stream);
  attn_kernel<0><<<dim3(64, TT/8), 256, 0, stream>>>(qkv, deltab);
  launch_gemm(0, deltab, ca_out_w, ca_out_b, nullptr, ybuf, ROWS, 512, 512, 512, stream);
  launch_gemm(0, ybuf, ca_lin_w, ca_lin_b, hsb, fcur, ROWS, 512, 512, 512, stream);
  ln_kernel<<<ROWS,256,0,stream>>>(fcur, ca_ln_w, ca_ln_b, (float*)d_out);
}

// Round 3
// 11230.903 us; speedup vs baseline: 1.4527x; 1.4527x over previous
//
#include <hip/hip_runtime.h>
#include <math.h>

#define BB 8
#define TT 1024
#define DM 512
#define ROWS (BB*TT)     // 8192
#define ROWS1 (BB*(TT-1))// 8184
#define GRU_J 8          // hidden dims per block
#define GRU_GPB 64       // blocks per batch
#define GRU_BLK (BB*GRU_GPB)  // 512 blocks

__device__ __forceinline__ float sigm_(float v){ return 1.f/(1.f+expf(-v)); }

// ---------------- elementwise ----------------
__global__ __launch_bounds__(256) void delta_kernel(const float* __restrict__ x,
    const float* __restrict__ ts, float* __restrict__ delta)
{
  size_t i = (size_t)blockIdx.x*256 + threadIdx.x;
  int d = (int)(i & (DM-1));
  int r = (int)(i >> 9);
  int b = r / (TT-1), ii = r % (TT-1);
  float dt = ts[b*TT+ii+1] - ts[b*TT+ii];
  float x1 = x[((size_t)b*TT+ii+1)*DM + d];
  float x0 = x[((size_t)b*TT+ii)*DM + d];
  delta[i] = (x1 - x0) / dt;
}

template<int INIT, int WRITE_Y>
__global__ __launch_bounds__(256) void rk_kernel(float* __restrict__ acc,
    float* y, const float* __restrict__ delta,
    const float* __restrict__ f, const float* __restrict__ ts,
    float wa, float cy)
{
  size_t i = (size_t)blockIdx.x*256 + threadIdx.x;
  int r = (int)(i >> 9);
  int b = r / (TT-1), ii = r % (TT-1);
  float fv = f[i];
  float a = INIT ? 0.f : acc[i];
  acc[i] = a + wa*fv;
  if (WRITE_Y) {
    float dt = ts[b*TT+ii+1] - ts[b*TT+ii];
    y[i] = delta[i] + cy*dt*fv;
  }
}

__global__ __launch_bounds__(256) void states_kernel(const float* __restrict__ x,
    const float* __restrict__ ts, const float* __restrict__ acc,
    float* __restrict__ hin)
{
  size_t i = (size_t)blockIdx.x*256 + threadIdx.x;
  int d = (int)(i & (DM-1));
  int r = (int)(i >> 9);
  int b = r >> 10, t = r & (TT-1);
  float v = 0.f;
  if (t > 0) {
    int ii = t-1;
    float dt = ts[b*TT+ii+1] - ts[b*TT+ii];
    v = x[((size_t)b*TT+ii)*DM + d] + dt*(1.f/6.f)*acc[((size_t)b*(TT-1)+ii)*DM + d];
  }
  hin[i] = v;
}

__global__ __launch_bounds__(256) void timeenc_kernel(const float* __restrict__ x,
    const float* __restrict__ ts, const float* __restrict__ te_a,
    const float* __restrict__ te_b, float* __restrict__ z)
{
  size_t i = (size_t)blockIdx.x*256 + threadIdx.x;
  int d = (int)(i & (DM-1));
  int r = (int)(i >> 9);
  float t = ts[r];
  float tm;
  if (d & 1) {
    int j = d >> 1;                       // odd channels: ramp
    tm = t*te_a[j] + te_b[j];
  } else {
    int fi = d >> 2;                      // even: interleaved sin/cos
    float fr = expf(-(float)fi * 0.061606661f) * 1.5707964f; // exp(-i*ln(2500)/127)*pi/2
    float ph = t * fr;
    tm = ((d & 3) == 0) ? sinf(ph) : cosf(ph);
  }
  z[i] = x[i] + tm;
}

// ---------------- LayerNorm (block per row, D=512) ----------------
__global__ __launch_bounds__(256) void ln_kernel(const float* __restrict__ x,
    const float* __restrict__ w, const float* __restrict__ b,
    float* __restrict__ out)
{
  int row = blockIdx.x;
  int tid = threadIdx.x;
  const float* xr = x + (size_t)row*DM;
  float2 v = *(const float2*)(xr + tid*2);
  float s = v.x+v.y, sq = v.x*v.x + v.y*v.y;
  #pragma unroll
  for (int off=1; off<64; off<<=1){ s += __shfl_xor(s,off); sq += __shfl_xor(sq,off); }
  __shared__ float rs[4], rq[4];
  int wid = tid>>6;
  if ((tid&63)==0){ rs[wid]=s; rq[wid]=sq; }
  __syncthreads();
  s = rs[0]+rs[1]+rs[2]+rs[3];
  sq = rq[0]+rq[1]+rq[2]+rq[3];
  float mean = s*(1.f/DM);
  float var = sq*(1.f/DM) - mean*mean;
  float inv = rsqrtf(var + 1e-5f);
  float2 wv = *(const float2*)(w + tid*2);
  float2 bv = *(const float2*)(b + tid*2);
  float2 o;
  o.x = (v.x-mean)*inv*wv.x + bv.x;
  o.y = (v.y-mean)*inv*wv.y + bv.y;
  *(float2*)(out + (size_t)row*DM + tid*2) = o;
}

// ---------------- GEMM: C[m][n] = act(dot(A[m,:],W[n,:]) + bias[n]) (+res) ----------------
template<int ACT>  // 0 none, 1 relu, 2 tanh
__global__ __launch_bounds__(256) void gemm_kernel(
    const float* __restrict__ A, const float* __restrict__ W,
    const float* __restrict__ bias, const float* res,
    float* C, int M, int N, int K, int ldc)
{
  __shared__ float As[16][132];   // [k][m]
  __shared__ float Ws[16][68];    // [k][n]
  const int bm = blockIdx.y * 128;
  const int bn = blockIdx.x * 64;
  const int tid = threadIdx.x;
  const int rg = tid >> 4;        // 0..15
  const int cg = tid & 15;        // 0..15
  float acc[8][4];
  #pragma unroll
  for (int i=0;i<8;i++){
    #pragma unroll
    for (int j=0;j<4;j++) acc[i][j]=0.f;
  }
  const int ar = tid >> 1;            // 0..127
  const int ak = (tid & 1) * 8;
  const int wr = tid >> 2;            // 0..63
  const int wk = (tid & 3) * 4;

  for (int k0 = 0; k0 < K; k0 += 16) {
    float4 a0 = {0,0,0,0}, a1 = {0,0,0,0};
    int gr = bm + ar;
    if (gr < M) {
      const float* p = A + (size_t)gr * K + k0 + ak;
      a0 = *(const float4*)p;
      a1 = *(const float4*)(p + 4);
    }
    As[ak+0][ar]=a0.x; As[ak+1][ar]=a0.y; As[ak+2][ar]=a0.z; As[ak+3][ar]=a0.w;
    As[ak+4][ar]=a1.x; As[ak+5][ar]=a1.y; As[ak+6][ar]=a1.z; As[ak+7][ar]=a1.w;
    {
      const float* p = W + (size_t)(bn + wr) * K + k0 + wk;
      float4 w4 = *(const float4*)p;
      Ws[wk+0][wr]=w4.x; Ws[wk+1][wr]=w4.y; Ws[wk+2][wr]=w4.z; Ws[wk+3][wr]=w4.w;
    }
    __syncthreads();
    #pragma unroll
    for (int kk=0;kk<16;kk++) {
      float4 av0 = *(const float4*)&As[kk][rg*8];
      float4 av1 = *(const float4*)&As[kk][rg*8+4];
      float4 wv  = *(const float4*)&Ws[kk][cg*4];
      float am[8] = {av0.x,av0.y,av0.z,av0.w,av1.x,av1.y,av1.z,av1.w};
      float wm[4] = {wv.x,wv.y,wv.z,wv.w};
      #pragma unroll
      for (int i=0;i<8;i++){
        #pragma unroll
        for (int j=0;j<4;j++) acc[i][j] = fmaf(am[i], wm[j], acc[i][j]);
      }
    }
    __syncthreads();
  }
  const int gn0 = bn + cg*4;
  float4 bv = *(const float4*)(bias + gn0);
  #pragma unroll
  for (int i=0;i<8;i++) {
    int gm = bm + rg*8 + i;
    if (gm >= M) continue;
    float4 v;
    v.x = acc[i][0]+bv.x; v.y = acc[i][1]+bv.y;
    v.z = acc[i][2]+bv.z; v.w = acc[i][3]+bv.w;
    if (ACT==1){ v.x=fmaxf(v.x,0.f); v.y=fmaxf(v.y,0.f); v.z=fmaxf(v.z,0.f); v.w=fmaxf(v.w,0.f); }
    if (ACT==2){ v.x=tanhf(v.x); v.y=tanhf(v.y); v.z=tanhf(v.z); v.w=tanhf(v.w); }
    if (res) {
      float4 r4 = *(const float4*)(res + (size_t)gm*ldc + gn0);
      v.x+=r4.x; v.y+=r4.y; v.z+=r4.z; v.w+=r4.w;
    }
    *(float4*)(C + (size_t)gm*ldc + gn0) = v;
  }
}

// ---------------- attention ----------------
template<int CAUSAL>
__global__ __launch_bounds__(256) void attn_kernel(const float* __restrict__ QKV,
                                                   float* __restrict__ O)
{
  __shared__ float qt[8][68];
  __shared__ float kt[32][68];
  __shared__ float vt[32][68];
  __shared__ float sc[8][1028];
  const int bh = blockIdx.x;
  const int b = bh >> 3, h = bh & 7;
  const int q0 = blockIdx.y * 8;
  const int tid = threadIdx.x;
  const int qrow = tid >> 5;       // 0..7
  const int klane = tid & 31;      // 0..31
  const float* base = QKV + (size_t)b*TT*1536;
  for (int idx = tid; idx < 8*64; idx += 256) {
    int q = idx >> 6, d = idx & 63;
    qt[q][d] = base[(size_t)(q0+q)*1536 + h*64 + d];
  }
  const int nkt = CAUSAL ? (q0/32 + 1) : (TT/32);
  for (int t0 = 0; t0 < nkt; t0++) {
    __syncthreads();
    for (int idx = tid; idx < 32*64; idx += 256) {
      int kk = idx >> 6, d = idx & 63;
      kt[kk][d] = base[(size_t)(t0*32+kk)*1536 + 512 + h*64 + d];
    }
    __syncthreads();
    float s = 0.f;
    #pragma unroll
    for (int d = 0; d < 64; d += 4) {
      float4 qv = *(const float4*)&qt[qrow][d];
      float4 kv = *(const float4*)&kt[klane][d];
      s += qv.x*kv.x + qv.y*kv.y + qv.z*kv.z + qv.w*kv.w;
    }
    int kg = t0*32 + klane;
    s *= 0.125f;
    if (CAUSAL && kg > q0 + qrow) s = -1e30f;
    sc[qrow][kg] = s;
  }
  __syncthreads();
  const int nk = nkt*32;
  float mx = -1e30f;
  for (int k = klane; k < nk; k += 32) mx = fmaxf(mx, sc[qrow][k]);
  #pragma unroll
  for (int off=1; off<32; off<<=1) mx = fmaxf(mx, __shfl_xor(mx, off));
  float sum = 0.f;
  for (int k = klane; k < nk; k += 32) { float e = expf(sc[qrow][k]-mx); sc[qrow][k]=e; sum += e; }
  #pragma unroll
  for (int off=1; off<32; off<<=1) sum += __shfl_xor(sum, off);
  float inv = 1.f/sum;
  for (int k = klane; k < nk; k += 32) sc[qrow][k] *= inv;
  float o0=0.f, o1=0.f;
  for (int t0 = 0; t0 < nkt; t0++) {
    __syncthreads();
    for (int idx = tid; idx < 32*64; idx += 256) {
      int kk = idx >> 6, d = idx & 63;
      vt[kk][d] = base[(size_t)(t0*32+kk)*1536 + 1024 + h*64 + d];
    }
    __syncthreads();
    #pragma unroll
    for (int kk=0; kk<32; kk++) {
      float p = sc[qrow][t0*32+kk];
      o0 += p*vt[kk][klane];
      o1 += p*vt[kk][klane+32];
    }
  }
  float* op = O + (size_t)(b*TT + q0 + qrow)*DM + h*64 + klane;
  op[0]  = o0;
  op[32] = o1;
}

// ---------------- GRU scan v3: relaxed-atomics-only sync (NO fences) ----------------
// 512 blocks = 8 batches x 64 slices of 8 hidden dims; batch = blk&7 pins each
// batch's pipeline to one XCD (default round-robin dispatch). All cross-block
// traffic (h ping-pong + progress flags) uses RELAXED agent-scope atomics,
// which read/write the coherence point directly with NO L2 writeback/invalidate
// (the v1/v2 killer). Writer ordering: h atomic-stores -> s_waitcnt vmcnt(0)
// (same wave, explicit inline asm) -> flag atomic-store.
__global__ __launch_bounds__(256) void gru_scan_kernel(
    const float* __restrict__ gx,   // (B*T,1536) includes bih
    const float* __restrict__ whh,  // (1536,512)
    const float* __restrict__ bhh,  // (1536)
    float* __restrict__ Hs,         // (B*T,512)
    float* hbuf,                    // 2 * B*512 ping-pong
    int* flags)                     // B*64 progress flags (memset 0)
{
  __shared__ float wlds[3*GRU_J*516];
  __shared__ float hsp[512];
  __shared__ float red[4][3][GRU_J];
  __shared__ float gxs[3][GRU_J];

  const int blk = blockIdx.x;
  const int b = blk & 7;           // batch -> XCD (round-robin dispatch)
  const int g = blk >> 3;          // slice 0..63
  const int j0 = g * GRU_J;
  const int tid = threadIdx.x;
  const int lane = tid & 63;
  const int wv = tid >> 6;

  for (int idx = tid; idx < 3*GRU_J*512; idx += 256) {
    int gate = idx >> 12;          // /(8*512)
    int rem  = idx & 4095;
    int jj2  = rem >> 9, k = rem & 511;
    wlds[(gate*GRU_J+jj2)*516 + k] = whh[(size_t)(gate*512 + j0 + jj2)*512 + k];
  }
  float bh0=0.f, bh1=0.f, bh2=0.f;
  if (tid < GRU_J) {
    bh0 = bhh[j0+tid]; bh1 = bhh[512+j0+tid]; bh2 = bhh[1024+j0+tid];
  }
  const int jj = tid & (GRU_J-1);
  const int kc = tid >> 3;          // 0..31, K-chunk of 16
  const int k0 = kc*16;
  const float* w0p = &wlds[(0*GRU_J+jj)*516 + k0];
  const float* w1p = &wlds[(1*GRU_J+jj)*516 + k0];
  const float* w2p = &wlds[(2*GRU_J+jj)*516 + k0];
  __syncthreads();

  for (int t = 0; t < TT; t++) {
    // gx load issued before the poll so its latency hides under the wait
    float gxv = 0.f;
    if (tid < 3*GRU_J) {
      int gate = tid >> 3, j = tid & 7;
      gxv = gx[((size_t)b*TT + t)*1536 + gate*512 + j0 + j];
    }
    if (t > 0) {
      if (wv == 0) {
        for (;;) {
          int f = __hip_atomic_load(&flags[b*GRU_GPB + lane],
                                    __ATOMIC_RELAXED, __HIP_MEMORY_SCOPE_AGENT);
          if (__all(f >= t)) break;
          __builtin_amdgcn_s_sleep(1);
        }
      }
      __syncthreads();
      const float* src = hbuf + ((((t&1)^1)*BB + b) << 9);
      float h0 = __hip_atomic_load(src + tid,       __ATOMIC_RELAXED, __HIP_MEMORY_SCOPE_AGENT);
      float h1 = __hip_atomic_load(src + 256 + tid, __ATOMIC_RELAXED, __HIP_MEMORY_SCOPE_AGENT);
      hsp[tid] = h0; hsp[256+tid] = h1;
    } else {
      hsp[tid] = 0.f; hsp[256+tid] = 0.f;
    }
    if (tid < 3*GRU_J) gxs[tid>>3][tid&7] = gxv;
    __syncthreads();

    float s0=0.f, s1=0.f, s2=0.f;
    #pragma unroll
    for (int q = 0; q < 4; q++) {
      int qq = (((kc>>1) + q) & 3) * 4;   // rotate quarters: spread LDS banks
      float4 h4 = *(const float4*)&hsp[k0 + qq];
      float4 a = *(const float4*)(w0p + qq);
      float4 c = *(const float4*)(w1p + qq);
      float4 d = *(const float4*)(w2p + qq);
      s0 += a.x*h4.x + a.y*h4.y + a.z*h4.z + a.w*h4.w;
      s1 += c.x*h4.x + c.y*h4.y + c.z*h4.z + c.w*h4.w;
      s2 += d.x*h4.x + d.y*h4.y + d.z*h4.z + d.w*h4.w;
    }
    #pragma unroll
    for (int off = 8; off < 64; off <<= 1) {
      s0 += __shfl_xor(s0, off);
      s1 += __shfl_xor(s1, off);
      s2 += __shfl_xor(s2, off);
    }
    if (lane < GRU_J) {
      red[wv][0][lane] = s0; red[wv][1][lane] = s1; red[wv][2][lane] = s2;
    }
    __syncthreads();
    if (tid < GRU_J) {
      float sr = red[0][0][tid]+red[1][0][tid]+red[2][0][tid]+red[3][0][tid];
      float sz = red[0][1][tid]+red[1][1][tid]+red[2][1][tid]+red[3][1][tid];
      float sn = red[0][2][tid]+red[1][2][tid]+red[2][2][tid]+red[3][2][tid];
      float r  = sigm_(gxs[0][tid] + sr + bh0);
      float z  = sigm_(gxs[1][tid] + sz + bh1);
      float n  = tanhf(gxs[2][tid] + r*(sn + bh2));
      float hold = hsp[j0 + tid];
      float hnew = (1.f - z)*n + z*hold;
      Hs[((size_t)b*TT + t)*DM + j0 + tid] = hnew;
      __hip_atomic_store(&hbuf[(((t&1)*BB + b) << 9) + j0 + tid], hnew,
                         __ATOMIC_RELAXED, __HIP_MEMORY_SCOPE_AGENT);
    }
    if (tid == 0) {
      // h stores were issued by THIS wave (lanes 0..7); vmcnt is per-wave, so
      // draining it here guarantees they reached the coherence point before
      // the flag becomes visible. No cache maintenance.
      asm volatile("s_waitcnt vmcnt(0)" ::: "memory");
      __hip_atomic_store(&flags[b*GRU_GPB + g], t+1,
                         __ATOMIC_RELAXED, __HIP_MEMORY_SCOPE_AGENT);
    }
    __syncthreads();
  }
}

// ---------------- host ----------------
static void launch_gemm(int act, const float* A, const float* W, const float* bias,
                        const float* res, float* C, int M, int N, int K, int ldc,
                        hipStream_t stream)
{
  dim3 grid(N/64, (M+127)/128), blk(256);
  switch(act){
    case 1: gemm_kernel<1><<<grid,blk,0,stream>>>(A,W,bias,res,C,M,N,K,ldc); break;
    case 2: gemm_kernel<2><<<grid,blk,0,stream>>>(A,W,bias,res,C,M,N,K,ldc); break;
    default: gemm_kernel<0><<<grid,blk,0,stream>>>(A,W,bias,res,C,M,N,K,ldc); break;
  }
}

extern "C" void kernel_launch(void* const* d_in, const int* in_sizes, int n_in,
                              void* d_out, int out_size, void* d_ws, size_t ws_size,
                              hipStream_t stream)
{
  (void)in_sizes; (void)n_in; (void)out_size; (void)ws_size;
  const float* x       = (const float*)d_in[0];
  const float* ts      = (const float*)d_in[1];
  const float* ode_w1  = (const float*)d_in[2];
  const float* ode_b1  = (const float*)d_in[3];
  const float* ode_w2  = (const float*)d_in[4];
  const float* ode_b2  = (const float*)d_in[5];
  const float* gru_wih = (const float*)d_in[6];
  const float* gru_whh = (const float*)d_in[7];
  const float* gru_bih = (const float*)d_in[8];
  const float* gru_bhh = (const float*)d_in[9];
  const float* te_a    = (const float*)d_in[10];
  const float* te_b    = (const float*)d_in[11];
  const float* t_in_w  = (const float*)d_in[12];
  const float* t_in_b  = (const float*)d_in[13];
  const float* t_out_w = (const float*)d_in[14];
  const float* t_out_b = (const float*)d_in[15];
  const float* t_ln1_w = (const float*)d_in[16];
  const float* t_ln1_b = (const float*)d_in[17];
  const float* t_ln2_w = (const float*)d_in[18];
  const float* t_ln2_b = (const float*)d_in[19];
  const float* t_ff1_w = (const float*)d_in[20];
  const float* t_ff1_b = (const float*)d_in[21];
  const float* t_ff2_w = (const float*)d_in[22];
  const float* t_ff2_b = (const float*)d_in[23];
  const float* t_lnf_w = (const float*)d_in[24];
  const float* t_lnf_b = (const float*)d_in[25];
  const float* ca_in_w = (const float*)d_in[26];
  const float* ca_in_b = (const float*)d_in[27];
  const float* ca_out_w= (const float*)d_in[28];
  const float* ca_out_b= (const float*)d_in[29];
  const float* ca_lin_w= (const float*)d_in[30];
  const float* ca_lin_b= (const float*)d_in[31];
  const float* ca_ln_w = (const float*)d_in[32];
  const float* ca_ln_b = (const float*)d_in[33];

  float* ws = (float*)d_ws;
  const size_t SZ = (size_t)ROWS * DM;      // 4M floats = 16MB
  float* deltab = ws + 0*SZ;                // ODE delta; later attn O
  float* ycur   = ws + 1*SZ;
  float* fcur   = ws + 2*SZ;                // later cross-attn pre-LN
  float* accb   = ws + 3*SZ;
  float* ff1    = ws + 0*SZ;                // aliases [0,4SZ) (ODE bufs dead by then)
  float* ybuf   = ws + 4*SZ;                // tanh tmp / LN y / cross AO
  float* hin    = ws + 5*SZ;                // H_in; later zf
  float* qkv    = ws + 6*SZ;                // 3*SZ: gx, later QKV
  float* hsb    = ws + 9*SZ;                // GRU output H (persists)
  float* zbuf   = ws + 10*SZ;               // transformer stream
  float* hbuf   = ws + 11*SZ;               // 2*B*512 GRU h ping-pong
  int*   flags  = (int*)(ws + 11*SZ + 2*BB*512);

  hipMemsetAsync(flags, 0, GRU_BLK*sizeof(int), stream);

  // ---- ODE (RK4 over parallel states) ----
  delta_kernel<<<ROWS1*DM/256, 256, 0, stream>>>(x, ts, deltab);
  const float* yin = deltab;
  const float was[4] = {1.f, 2.f, 2.f, 1.f};
  const float cys[4] = {0.5f, 0.5f, 1.f, 0.f};
  for (int s4 = 0; s4 < 4; s4++) {
    launch_gemm(2, yin, ode_w1, ode_b1, nullptr, ybuf, ROWS1, 512, 512, 512, stream);
    launch_gemm(0, ybuf, ode_w2, ode_b2, nullptr, fcur, ROWS1, 512, 512, 512, stream);
    if (s4 == 0)
      rk_kernel<1,1><<<ROWS1*DM/256,256,0,stream>>>(accb, ycur, deltab, fcur, ts, was[s4], cys[s4]);
    else if (s4 < 3)
      rk_kernel<0,1><<<ROWS1*DM/256,256,0,stream>>>(accb, ycur, deltab, fcur, ts, was[s4], cys[s4]);
    else
      rk_kernel<0,0><<<ROWS1*DM/256,256,0,stream>>>(accb, nullptr, deltab, fcur, ts, was[s4], 0.f);
    yin = ycur;
  }
  states_kernel<<<ROWS*DM/256,256,0,stream>>>(x, ts, accb, hin);

  // ---- GRU ----
  launch_gemm(0, hin, gru_wih, gru_bih, nullptr, qkv, ROWS, 1536, 512, 1536, stream);
  gru_scan_kernel<<<GRU_BLK, 256, 0, stream>>>(qkv, gru_whh, gru_bhh, hsb, hbuf, flags);

  // ---- time encoding ----
  timeenc_kernel<<<ROWS*DM/256,256,0,stream>>>(x, ts, te_a, te_b, zbuf);

  // ---- transformer (2 layers, pre-norm, causal) ----
  for (int l = 0; l < 2; l++) {
    ln_kernel<<<ROWS,256,0,stream>>>(zbuf, t_ln1_w + l*512, t_ln1_b + l*512, ybuf);
    launch_gemm(0, ybuf, t_in_w + (size_t)l*1536*512, t_in_b + l*1536, nullptr, qkv, ROWS, 1536, 512, 1536, stream);
    attn_kernel<1><<<dim3(64, TT/8), 256, 0, stream>>>(qkv, deltab);
    launch_gemm(0, deltab, t_out_w + (size_t)l*512*512, t_out_b + l*512, zbuf, zbuf, ROWS, 512, 512, 512, stream);
    ln_kernel<<<ROWS,256,0,stream>>>(zbuf, t_ln2_w + l*512, t_ln2_b + l*512, ybuf);
    launch_gemm(1, ybuf, t_ff1_w + (size_t)l*2048*512, t_ff1_b + l*2048, nullptr, ff1, ROWS, 2048, 512, 2048, stream);
    launch_gemm(0, ff1, t_ff2_w + (size_t)l*512*2048, t_ff2_b + l*512, zbuf, zbuf, ROWS, 512, 2048, 512, stream);
  }
  ln_kernel<<<ROWS,256,0,stream>>>(zbuf, t_lnf_w, t_lnf_b, hin);   // hin = zf now

  // ---- cross attention: Q from Hs, K/V from zf ----
  launch_gemm(0, hsb, ca_in_w,            ca_in_b,       nullptr, qkv,       ROWS,  512, 512, 1536, stream);
  launch_gemm(0, hin, ca_in_w + 512*512,  ca_in_b + 512, nullptr, qkv + 512, ROWS, 1024, 512, 1536, stream);
  attn_kernel<0><<<dim3(64, TT/8), 256, 0, stream>>>(qkv, deltab);
  launch_gemm(0, deltab, ca_out_w, ca_out_b, nullptr, ybuf, ROWS, 512, 512, 512, stream);
  launch_gemm(0, ybuf, ca_lin_w, ca_lin_b, hsb, fcur, ROWS, 512, 512, 512, stream);
  ln_kernel<<<ROWS,256,0,stream>>>(fcur, ca_ln_w, ca_ln_b, (float*)d_out);
}

// Round 4
// 9909.972 us; speedup vs baseline: 1.6463x; 1.1333x over previous
//
#include <hip/hip_runtime.h>
#include <math.h>

#define BB 8
#define TT 1024
#define DM 512
#define ROWS (BB*TT)     // 8192
#define ROWS1 (BB*(TT-1))// 8184
#define GRU_J 8          // hidden dims per block
#define GRU_GPB 64       // blocks per batch
#define GRU_BLK (BB*GRU_GPB)  // 512 blocks

typedef __attribute__((ext_vector_type(4))) float f32x4;
typedef __attribute__((ext_vector_type(8))) short bf16x8;

__device__ __forceinline__ float sigm_(float v){ return 1.f/(1.f+expf(-v)); }

__device__ __forceinline__ unsigned short f2bf(float f){
  unsigned u = __float_as_uint(f);
  return (unsigned short)((u + 0x7FFFu + ((u>>16)&1u)) >> 16);
}

// ---------------- weight cast (f32 -> bf16, RNE) ----------------
__global__ __launch_bounds__(256) void castw_kernel(const float* __restrict__ w,
    unsigned short* __restrict__ o, int n4)
{
  int i = blockIdx.x*256 + threadIdx.x;
  if (i < n4) {
    float4 v = ((const float4*)w)[i];
    ushort4 u;
    u.x = f2bf(v.x); u.y = f2bf(v.y); u.z = f2bf(v.z); u.w = f2bf(v.w);
    ((ushort4*)o)[i] = u;
  }
}

// ---------------- elementwise ----------------
__global__ __launch_bounds__(256) void delta_kernel(const float* __restrict__ x,
    const float* __restrict__ ts, float* __restrict__ delta)
{
  size_t i = (size_t)blockIdx.x*256 + threadIdx.x;
  int d = (int)(i & (DM-1));
  int r = (int)(i >> 9);
  int b = r / (TT-1), ii = r % (TT-1);
  float dt = ts[b*TT+ii+1] - ts[b*TT+ii];
  float x1 = x[((size_t)b*TT+ii+1)*DM + d];
  float x0 = x[((size_t)b*TT+ii)*DM + d];
  delta[i] = (x1 - x0) / dt;
}

template<int INIT, int WRITE_Y>
__global__ __launch_bounds__(256) void rk_kernel(float* __restrict__ acc,
    float* y, const float* __restrict__ delta,
    const float* __restrict__ f, const float* __restrict__ ts,
    float wa, float cy)
{
  size_t i = (size_t)blockIdx.x*256 + threadIdx.x;
  int r = (int)(i >> 9);
  int b = r / (TT-1), ii = r % (TT-1);
  float fv = f[i];
  float a = INIT ? 0.f : acc[i];
  acc[i] = a + wa*fv;
  if (WRITE_Y) {
    float dt = ts[b*TT+ii+1] - ts[b*TT+ii];
    y[i] = delta[i] + cy*dt*fv;
  }
}

__global__ __launch_bounds__(256) void states_kernel(const float* __restrict__ x,
    const float* __restrict__ ts, const float* __restrict__ acc,
    float* __restrict__ hin)
{
  size_t i = (size_t)blockIdx.x*256 + threadIdx.x;
  int d = (int)(i & (DM-1));
  int r = (int)(i >> 9);
  int b = r >> 10, t = r & (TT-1);
  float v = 0.f;
  if (t > 0) {
    int ii = t-1;
    float dt = ts[b*TT+ii+1] - ts[b*TT+ii];
    v = x[((size_t)b*TT+ii)*DM + d] + dt*(1.f/6.f)*acc[((size_t)b*(TT-1)+ii)*DM + d];
  }
  hin[i] = v;
}

__global__ __launch_bounds__(256) void timeenc_kernel(const float* __restrict__ x,
    const float* __restrict__ ts, const float* __restrict__ te_a,
    const float* __restrict__ te_b, float* __restrict__ z)
{
  size_t i = (size_t)blockIdx.x*256 + threadIdx.x;
  int d = (int)(i & (DM-1));
  int r = (int)(i >> 9);
  float t = ts[r];
  float tm;
  if (d & 1) {
    int j = d >> 1;                       // odd channels: ramp
    tm = t*te_a[j] + te_b[j];
  } else {
    int fi = d >> 2;                      // even: interleaved sin/cos
    float fr = expf(-(float)fi * 0.061606661f) * 1.5707964f; // exp(-i*ln(2500)/127)*pi/2
    float ph = t * fr;
    tm = ((d & 3) == 0) ? sinf(ph) : cosf(ph);
  }
  z[i] = x[i] + tm;
}

// ---------------- LayerNorm (block per row, D=512) ----------------
__global__ __launch_bounds__(256) void ln_kernel(const float* __restrict__ x,
    const float* __restrict__ w, const float* __restrict__ b,
    float* __restrict__ out)
{
  int row = blockIdx.x;
  int tid = threadIdx.x;
  const float* xr = x + (size_t)row*DM;
  float2 v = *(const float2*)(xr + tid*2);
  float s = v.x+v.y, sq = v.x*v.x + v.y*v.y;
  #pragma unroll
  for (int off=1; off<64; off<<=1){ s += __shfl_xor(s,off); sq += __shfl_xor(sq,off); }
  __shared__ float rs[4], rq[4];
  int wid = tid>>6;
  if ((tid&63)==0){ rs[wid]=s; rq[wid]=sq; }
  __syncthreads();
  s = rs[0]+rs[1]+rs[2]+rs[3];
  sq = rq[0]+rq[1]+rq[2]+rq[3];
  float mean = s*(1.f/DM);
  float var = sq*(1.f/DM) - mean*mean;
  float inv = rsqrtf(var + 1e-5f);
  float2 wv = *(const float2*)(w + tid*2);
  float2 bv = *(const float2*)(b + tid*2);
  float2 o;
  o.x = (v.x-mean)*inv*wv.x + bv.x;
  o.y = (v.y-mean)*inv*wv.y + bv.y;
  *(float2*)(out + (size_t)row*DM + tid*2) = o;
}

// ---------------- bf16 MFMA GEMM: C = act(A @ Wb^T + bias) (+res) ----------------
// A: MxK f32 row-major (converted to bf16 while staging). Wb: NxK bf16 row-major.
// 128x128 tile, BK=32, 4 waves each 64x64 (4x4 frags of 16x16x32).
// LDS rows padded to 40 bf16 (80B) -> <=2-way aliasing on ds_read_b128 (free).
template<int ACT>  // 0 none, 1 relu, 2 tanh
__global__ __launch_bounds__(256) void bgemm_kernel(
    const float* __restrict__ A, const unsigned short* __restrict__ Wb,
    const float* __restrict__ bias, const float* res,
    float* __restrict__ C, int M, int N, int K, int ldc)
{
  __shared__ __align__(16) unsigned short Al[2][128][40];
  __shared__ __align__(16) unsigned short Wl[2][128][40];
  const int bm = blockIdx.y*128, bn = blockIdx.x*128;
  const int tid = threadIdx.x;
  const int lane = tid & 63, wid = tid >> 6;
  const int wm = (wid&1)*64, wn = (wid>>1)*64;
  const int fl = lane & 15, fk = (lane>>4)*8;   // frag: row/col fl, k-offset fk
  const int sar = tid>>2, sac = (tid&3)*8;      // A staging: rows sar, sar+64
  const int swr = tid>>1, swc = (tid&1)*16;     // W staging: row swr, 16 bf16

  f32x4 acc[4][4];
  #pragma unroll
  for (int i=0;i<4;i++)
    #pragma unroll
    for (int j=0;j<4;j++) acc[i][j] = (f32x4){0.f,0.f,0.f,0.f};

  float4 areg[2][2];
  uint4  wreg[2];
  const int nk = K >> 5;

  auto load_t = [&](int kt){
    int k0 = kt*32;
    #pragma unroll
    for (int r=0;r<2;r++){
      int gr = bm + sar + r*64;
      if (gr < M) {
        const float* p = A + (size_t)gr*K + k0 + sac;
        areg[r][0] = *(const float4*)p;
        areg[r][1] = *(const float4*)(p+4);
      } else {
        areg[r][0] = make_float4(0.f,0.f,0.f,0.f);
        areg[r][1] = make_float4(0.f,0.f,0.f,0.f);
      }
    }
    const unsigned short* q = Wb + (size_t)(bn+swr)*K + k0 + swc;
    wreg[0] = *(const uint4*)q;
    wreg[1] = *(const uint4*)(q+8);
  };
  auto store_t = [&](int buf){
    #pragma unroll
    for (int r=0;r<2;r++){
      unsigned short h0=f2bf(areg[r][0].x), h1=f2bf(areg[r][0].y),
                     h2=f2bf(areg[r][0].z), h3=f2bf(areg[r][0].w),
                     h4=f2bf(areg[r][1].x), h5=f2bf(areg[r][1].y),
                     h6=f2bf(areg[r][1].z), h7=f2bf(areg[r][1].w);
      uint4 pk;
      pk.x = (unsigned)h0 | ((unsigned)h1<<16);
      pk.y = (unsigned)h2 | ((unsigned)h3<<16);
      pk.z = (unsigned)h4 | ((unsigned)h5<<16);
      pk.w = (unsigned)h6 | ((unsigned)h7<<16);
      *(uint4*)&Al[buf][sar + r*64][sac] = pk;
    }
    *(uint4*)&Wl[buf][swr][swc]     = wreg[0];
    *(uint4*)&Wl[buf][swr][swc+8]   = wreg[1];
  };

  load_t(0); store_t(0);
  int buf = 0;
  for (int kt = 0; kt < nk; ++kt) {
    __syncthreads();
    if (kt+1 < nk) load_t(kt+1);
    bf16x8 av[4], wv[4];
    #pragma unroll
    for (int i=0;i<4;i++) av[i] = *(const bf16x8*)&Al[buf][wm + i*16 + fl][fk];
    #pragma unroll
    for (int j=0;j<4;j++) wv[j] = *(const bf16x8*)&Wl[buf][wn + j*16 + fl][fk];
    #pragma unroll
    for (int i=0;i<4;i++)
      #pragma unroll
      for (int j=0;j<4;j++)
        acc[i][j] = __builtin_amdgcn_mfma_f32_16x16x32_bf16(av[i], wv[j], acc[i][j], 0, 0, 0);
    if (kt+1 < nk) store_t(buf^1);
    buf ^= 1;
  }

  // epilogue: C/D layout col=lane&15, row=(lane>>4)*4+reg  [m89-verified]
  #pragma unroll
  for (int j=0;j<4;j++){
    int gn = bn + wn + j*16 + fl;
    float bv = bias[gn];
    #pragma unroll
    for (int i=0;i<4;i++){
      #pragma unroll
      for (int r=0;r<4;r++){
        int gm = bm + wm + i*16 + (lane>>4)*4 + r;
        if (gm >= M) continue;
        float v = acc[i][j][r] + bv;
        if (ACT==1) v = fmaxf(v, 0.f);
        if (ACT==2) v = tanhf(v);
        if (res) v += res[(size_t)gm*ldc + gn];
        C[(size_t)gm*ldc + gn] = v;
      }
    }
  }
}

// ---------------- attention ----------------
template<int CAUSAL>
__global__ __launch_bounds__(256) void attn_kernel(const float* __restrict__ QKV,
                                                   float* __restrict__ O)
{
  __shared__ float qt[8][68];
  __shared__ float kt[32][68];
  __shared__ float vt[32][68];
  __shared__ float sc[8][1028];
  const int bh = blockIdx.x;
  const int b = bh >> 3, h = bh & 7;
  const int q0 = blockIdx.y * 8;
  const int tid = threadIdx.x;
  const int qrow = tid >> 5;       // 0..7
  const int klane = tid & 31;      // 0..31
  const float* base = QKV + (size_t)b*TT*1536;
  for (int idx = tid; idx < 8*64; idx += 256) {
    int q = idx >> 6, d = idx & 63;
    qt[q][d] = base[(size_t)(q0+q)*1536 + h*64 + d];
  }
  const int nkt = CAUSAL ? (q0/32 + 1) : (TT/32);
  for (int t0 = 0; t0 < nkt; t0++) {
    __syncthreads();
    for (int idx = tid; idx < 32*64; idx += 256) {
      int kk = idx >> 6, d = idx & 63;
      kt[kk][d] = base[(size_t)(t0*32+kk)*1536 + 512 + h*64 + d];
    }
    __syncthreads();
    float s = 0.f;
    #pragma unroll
    for (int d = 0; d < 64; d += 4) {
      float4 qv = *(const float4*)&qt[qrow][d];
      float4 kv = *(const float4*)&kt[klane][d];
      s += qv.x*kv.x + qv.y*kv.y + qv.z*kv.z + qv.w*kv.w;
    }
    int kg = t0*32 + klane;
    s *= 0.125f;
    if (CAUSAL && kg > q0 + qrow) s = -1e30f;
    sc[qrow][kg] = s;
  }
  __syncthreads();
  const int nk = nkt*32;
  float mx = -1e30f;
  for (int k = klane; k < nk; k += 32) mx = fmaxf(mx, sc[qrow][k]);
  #pragma unroll
  for (int off=1; off<32; off<<=1) mx = fmaxf(mx, __shfl_xor(mx, off));
  float sum = 0.f;
  for (int k = klane; k < nk; k += 32) { float e = expf(sc[qrow][k]-mx); sc[qrow][k]=e; sum += e; }
  #pragma unroll
  for (int off=1; off<32; off<<=1) sum += __shfl_xor(sum, off);
  float inv = 1.f/sum;
  for (int k = klane; k < nk; k += 32) sc[qrow][k] *= inv;
  float o0=0.f, o1=0.f;
  for (int t0 = 0; t0 < nkt; t0++) {
    __syncthreads();
    for (int idx = tid; idx < 32*64; idx += 256) {
      int kk = idx >> 6, d = idx & 63;
      vt[kk][d] = base[(size_t)(t0*32+kk)*1536 + 1024 + h*64 + d];
    }
    __syncthreads();
    #pragma unroll
    for (int kk=0; kk<32; kk++) {
      float p = sc[qrow][t0*32+kk];
      o0 += p*vt[kk][klane];
      o1 += p*vt[kk][klane+32];
    }
  }
  float* op = O + (size_t)(b*TT + q0 + qrow)*DM + h*64 + klane;
  op[0]  = o0;
  op[32] = o1;
}

// ---------------- GRU scan v3: relaxed-atomics-only sync (NO fences) ----------------
__global__ __launch_bounds__(256) void gru_scan_kernel(
    const float* __restrict__ gx,   // (B*T,1536) includes bih
    const float* __restrict__ whh,  // (1536,512)
    const float* __restrict__ bhh,  // (1536)
    float* __restrict__ Hs,         // (B*T,512)
    float* hbuf,                    // 2 * B*512 ping-pong
    int* flags)                     // B*64 progress flags (memset 0)
{
  __shared__ float wlds[3*GRU_J*516];
  __shared__ float hsp[512];
  __shared__ float red[4][3][GRU_J];
  __shared__ float gxs[3][GRU_J];

  const int blk = blockIdx.x;
  const int b = blk & 7;           // batch -> XCD (round-robin dispatch)
  const int g = blk >> 3;          // slice 0..63
  const int j0 = g * GRU_J;
  const int tid = threadIdx.x;
  const int lane = tid & 63;
  const int wv = tid >> 6;

  for (int idx = tid; idx < 3*GRU_J*512; idx += 256) {
    int gate = idx >> 12;
    int rem  = idx & 4095;
    int jj2  = rem >> 9, k = rem & 511;
    wlds[(gate*GRU_J+jj2)*516 + k] = whh[(size_t)(gate*512 + j0 + jj2)*512 + k];
  }
  float bh0=0.f, bh1=0.f, bh2=0.f;
  if (tid < GRU_J) {
    bh0 = bhh[j0+tid]; bh1 = bhh[512+j0+tid]; bh2 = bhh[1024+j0+tid];
  }
  const int jj = tid & (GRU_J-1);
  const int kc = tid >> 3;
  const int k0 = kc*16;
  const float* w0p = &wlds[(0*GRU_J+jj)*516 + k0];
  const float* w1p = &wlds[(1*GRU_J+jj)*516 + k0];
  const float* w2p = &wlds[(2*GRU_J+jj)*516 + k0];
  __syncthreads();

  for (int t = 0; t < TT; t++) {
    float gxv = 0.f;
    if (tid < 3*GRU_J) {
      int gate = tid >> 3, j = tid & 7;
      gxv = gx[((size_t)b*TT + t)*1536 + gate*512 + j0 + j];
    }
    if (t > 0) {
      if (wv == 0) {
        for (;;) {
          int f = __hip_atomic_load(&flags[b*GRU_GPB + lane],
                                    __ATOMIC_RELAXED, __HIP_MEMORY_SCOPE_AGENT);
          if (__all(f >= t)) break;
          __builtin_amdgcn_s_sleep(1);
        }
      }
      __syncthreads();
      const float* src = hbuf + ((((t&1)^1)*BB + b) << 9);
      float h0 = __hip_atomic_load(src + tid,       __ATOMIC_RELAXED, __HIP_MEMORY_SCOPE_AGENT);
      float h1 = __hip_atomic_load(src + 256 + tid, __ATOMIC_RELAXED, __HIP_MEMORY_SCOPE_AGENT);
      hsp[tid] = h0; hsp[256+tid] = h1;
    } else {
      hsp[tid] = 0.f; hsp[256+tid] = 0.f;
    }
    if (tid < 3*GRU_J) gxs[tid>>3][tid&7] = gxv;
    __syncthreads();

    float s0=0.f, s1=0.f, s2=0.f;
    #pragma unroll
    for (int q = 0; q < 4; q++) {
      int qq = (((kc>>1) + q) & 3) * 4;
      float4 h4 = *(const float4*)&hsp[k0 + qq];
      float4 a = *(const float4*)(w0p + qq);
      float4 c = *(const float4*)(w1p + qq);
      float4 d = *(const float4*)(w2p + qq);
      s0 += a.x*h4.x + a.y*h4.y + a.z*h4.z + a.w*h4.w;
      s1 += c.x*h4.x + c.y*h4.y + c.z*h4.z + c.w*h4.w;
      s2 += d.x*h4.x + d.y*h4.y + d.z*h4.z + d.w*h4.w;
    }
    #pragma unroll
    for (int off = 8; off < 64; off <<= 1) {
      s0 += __shfl_xor(s0, off);
      s1 += __shfl_xor(s1, off);
      s2 += __shfl_xor(s2, off);
    }
    if (lane < GRU_J) {
      red[wv][0][lane] = s0; red[wv][1][lane] = s1; red[wv][2][lane] = s2;
    }
    __syncthreads();
    if (tid < GRU_J) {
      float sr = red[0][0][tid]+red[1][0][tid]+red[2][0][tid]+red[3][0][tid];
      float sz = red[0][1][tid]+red[1][1][tid]+red[2][1][tid]+red[3][1][tid];
      float sn = red[0][2][tid]+red[1][2][tid]+red[2][2][tid]+red[3][2][tid];
      float r  = sigm_(gxs[0][tid] + sr + bh0);
      float z  = sigm_(gxs[1][tid] + sz + bh1);
      float n  = tanhf(gxs[2][tid] + r*(sn + bh2));
      float hold = hsp[j0 + tid];
      float hnew = (1.f - z)*n + z*hold;
      Hs[((size_t)b*TT + t)*DM + j0 + tid] = hnew;
      __hip_atomic_store(&hbuf[(((t&1)*BB + b) << 9) + j0 + tid], hnew,
                         __ATOMIC_RELAXED, __HIP_MEMORY_SCOPE_AGENT);
    }
    if (tid == 0) {
      asm volatile("s_waitcnt vmcnt(0)" ::: "memory");
      __hip_atomic_store(&flags[b*GRU_GPB + g], t+1,
                         __ATOMIC_RELAXED, __HIP_MEMORY_SCOPE_AGENT);
    }
    __syncthreads();
  }
}

// ---------------- host ----------------
static void launch_bgemm(int act, const float* A, const unsigned short* Wb,
                         const float* bias, const float* res, float* C,
                         int M, int N, int K, int ldc, hipStream_t stream)
{
  dim3 grid(N/128, (M+127)/128), blk(256);
  switch(act){
    case 1: bgemm_kernel<1><<<grid,blk,0,stream>>>(A,Wb,bias,res,C,M,N,K,ldc); break;
    case 2: bgemm_kernel<2><<<grid,blk,0,stream>>>(A,Wb,bias,res,C,M,N,K,ldc); break;
    default: bgemm_kernel<0><<<grid,blk,0,stream>>>(A,Wb,bias,res,C,M,N,K,ldc); break;
  }
}

static unsigned short* cast_w(const float* w, unsigned short* dst, size_t n, hipStream_t s)
{
  castw_kernel<<<((int)(n/4)+255)/256, 256, 0, s>>>(w, dst, (int)(n/4));
  return dst + n;
}

extern "C" void kernel_launch(void* const* d_in, const int* in_sizes, int n_in,
                              void* d_out, int out_size, void* d_ws, size_t ws_size,
                              hipStream_t stream)
{
  (void)in_sizes; (void)n_in; (void)out_size; (void)ws_size;
  const float* x       = (const float*)d_in[0];
  const float* ts      = (const float*)d_in[1];
  const float* ode_w1  = (const float*)d_in[2];
  const float* ode_b1  = (const float*)d_in[3];
  const float* ode_w2  = (const float*)d_in[4];
  const float* ode_b2  = (const float*)d_in[5];
  const float* gru_wih = (const float*)d_in[6];
  const float* gru_whh = (const float*)d_in[7];
  const float* gru_bih = (const float*)d_in[8];
  const float* gru_bhh = (const float*)d_in[9];
  const float* te_a    = (const float*)d_in[10];
  const float* te_b    = (const float*)d_in[11];
  const float* t_in_w  = (const float*)d_in[12];
  const float* t_in_b  = (const float*)d_in[13];
  const float* t_out_w = (const float*)d_in[14];
  const float* t_out_b = (const float*)d_in[15];
  const float* t_ln1_w = (const float*)d_in[16];
  const float* t_ln1_b = (const float*)d_in[17];
  const float* t_ln2_w = (const float*)d_in[18];
  const float* t_ln2_b = (const float*)d_in[19];
  const float* t_ff1_w = (const float*)d_in[20];
  const float* t_ff1_b = (const float*)d_in[21];
  const float* t_ff2_w = (const float*)d_in[22];
  const float* t_ff2_b = (const float*)d_in[23];
  const float* t_lnf_w = (const float*)d_in[24];
  const float* t_lnf_b = (const float*)d_in[25];
  const float* ca_in_w = (const float*)d_in[26];
  const float* ca_in_b = (const float*)d_in[27];
  const float* ca_out_w= (const float*)d_in[28];
  const float* ca_out_b= (const float*)d_in[29];
  const float* ca_lin_w= (const float*)d_in[30];
  const float* ca_lin_b= (const float*)d_in[31];
  const float* ca_ln_w = (const float*)d_in[32];
  const float* ca_ln_b = (const float*)d_in[33];

  float* ws = (float*)d_ws;
  const size_t SZ = (size_t)ROWS * DM;      // 4M floats = 16MB
  float* deltab = ws + 0*SZ;                // ODE delta; later attn O
  float* ycur   = ws + 1*SZ;
  float* fcur   = ws + 2*SZ;                // later cross-attn pre-LN
  float* accb   = ws + 3*SZ;
  float* ff1    = ws + 0*SZ;                // aliases [0,4SZ) (ODE bufs dead by then)
  float* ybuf   = ws + 4*SZ;                // tanh tmp / LN y / cross AO
  float* hin    = ws + 5*SZ;                // H_in; later zf
  float* qkv    = ws + 6*SZ;                // 3*SZ: gx, later QKV
  float* hsb    = ws + 9*SZ;                // GRU output H (persists)
  float* zbuf   = ws + 10*SZ;               // transformer stream
  float* hbuf   = ws + 11*SZ;               // 2*B*512 GRU h ping-pong
  int*   flags  = (int*)(ws + 11*SZ + 2*BB*512);

  // bf16 weight pool at 12*SZ (~18MB)
  unsigned short* wp = (unsigned short*)(ws + 12*SZ);
  unsigned short* wb_ode1 = wp;                         wp = cast_w(ode_w1,  wp, 512*512, stream);
  unsigned short* wb_ode2 = wp;                         wp = cast_w(ode_w2,  wp, 512*512, stream);
  unsigned short* wb_gwih = wp;                         wp = cast_w(gru_wih, wp, 1536*512, stream);
  unsigned short* wb_tin  = wp;                         wp = cast_w(t_in_w,  wp, (size_t)2*1536*512, stream);
  unsigned short* wb_tout = wp;                         wp = cast_w(t_out_w, wp, (size_t)2*512*512, stream);
  unsigned short* wb_ff1  = wp;                         wp = cast_w(t_ff1_w, wp, (size_t)2*2048*512, stream);
  unsigned short* wb_ff2  = wp;                         wp = cast_w(t_ff2_w, wp, (size_t)2*512*2048, stream);
  unsigned short* wb_cain = wp;                         wp = cast_w(ca_in_w, wp, 1536*512, stream);
  unsigned short* wb_caout= wp;                         wp = cast_w(ca_out_w,wp, 512*512, stream);
  unsigned short* wb_calin= wp;                         wp = cast_w(ca_lin_w,wp, 512*512, stream);

  hipMemsetAsync(flags, 0, GRU_BLK*sizeof(int), stream);

  // ---- ODE (RK4 over parallel states) ----
  delta_kernel<<<ROWS1*DM/256, 256, 0, stream>>>(x, ts, deltab);
  const float* yin = deltab;
  const float was[4] = {1.f, 2.f, 2.f, 1.f};
  const float cys[4] = {0.5f, 0.5f, 1.f, 0.f};
  for (int s4 = 0; s4 < 4; s4++) {
    launch_bgemm(2, yin, wb_ode1, ode_b1, nullptr, ybuf, ROWS1, 512, 512, 512, stream);
    launch_bgemm(0, ybuf, wb_ode2, ode_b2, nullptr, fcur, ROWS1, 512, 512, 512, stream);
    if (s4 == 0)
      rk_kernel<1,1><<<ROWS1*DM/256,256,0,stream>>>(accb, ycur, deltab, fcur, ts, was[s4], cys[s4]);
    else if (s4 < 3)
      rk_kernel<0,1><<<ROWS1*DM/256,256,0,stream>>>(accb, ycur, deltab, fcur, ts, was[s4], cys[s4]);
    else
      rk_kernel<0,0><<<ROWS1*DM/256,256,0,stream>>>(accb, nullptr, deltab, fcur, ts, was[s4], 0.f);
    yin = ycur;
  }
  states_kernel<<<ROWS*DM/256,256,0,stream>>>(x, ts, accb, hin);

  // ---- GRU ----
  launch_bgemm(0, hin, wb_gwih, gru_bih, nullptr, qkv, ROWS, 1536, 512, 1536, stream);
  gru_scan_kernel<<<GRU_BLK, 256, 0, stream>>>(qkv, gru_whh, gru_bhh, hsb, hbuf, flags);

  // ---- time encoding ----
  timeenc_kernel<<<ROWS*DM/256,256,0,stream>>>(x, ts, te_a, te_b, zbuf);

  // ---- transformer (2 layers, pre-norm, causal) ----
  for (int l = 0; l < 2; l++) {
    ln_kernel<<<ROWS,256,0,stream>>>(zbuf, t_ln1_w + l*512, t_ln1_b + l*512, ybuf);
    launch_bgemm(0, ybuf, wb_tin + (size_t)l*1536*512, t_in_b + l*1536, nullptr, qkv, ROWS, 1536, 512, 1536, stream);
    attn_kernel<1><<<dim3(64, TT/8), 256, 0, stream>>>(qkv, deltab);
    launch_bgemm(0, deltab, wb_tout + (size_t)l*512*512, t_out_b + l*512, zbuf, zbuf, ROWS, 512, 512, 512, stream);
    ln_kernel<<<ROWS,256,0,stream>>>(zbuf, t_ln2_w + l*512, t_ln2_b + l*512, ybuf);
    launch_bgemm(1, ybuf, wb_ff1 + (size_t)l*2048*512, t_ff1_b + l*2048, nullptr, ff1, ROWS, 2048, 512, 2048, stream);
    launch_bgemm(0, ff1, wb_ff2 + (size_t)l*512*2048, t_ff2_b + l*512, zbuf, zbuf, ROWS, 512, 2048, 512, stream);
  }
  ln_kernel<<<ROWS,256,0,stream>>>(zbuf, t_lnf_w, t_lnf_b, hin);   // hin = zf now

  // ---- cross attention: Q from Hs, K/V from zf ----
  launch_bgemm(0, hsb, wb_cain,            ca_in_b,       nullptr, qkv,       ROWS,  512, 512, 1536, stream);
  launch_bgemm(0, hin, wb_cain + 512*512,  ca_in_b + 512, nullptr, qkv + 512, ROWS, 1024, 512, 1536, stream);
  attn_kernel<0><<<dim3(64, TT/8), 256, 0, stream>>>(qkv, deltab);
  launch_bgemm(0, deltab, wb_caout, ca_out_b, nullptr, ybuf, ROWS, 512, 512, 512, stream);
  launch_bgemm(0, ybuf, wb_calin, ca_lin_b, hsb, fcur, ROWS, 512, 512, 512, stream);
  ln_kernel<<<ROWS,256,0,stream>>>(fcur, ca_ln_w, ca_ln_b, (float*)d_out);
}

// Round 5
// 5655.967 us; speedup vs baseline: 2.8845x; 1.7521x over previous
//
#include <hip/hip_runtime.h>
#include <math.h>

#define BB 8
#define TT 1024
#define DM 512
#define ROWS (BB*TT)     // 8192
#define ROWS1 (BB*(TT-1))// 8184
#define GRU_J 8          // hidden dims per block
#define GRU_BLK (BB*64)  // 512 blocks

typedef __attribute__((ext_vector_type(4))) float f32x4;
typedef __attribute__((ext_vector_type(8))) short bf16x8;

__device__ __forceinline__ float sigm_(float v){ return 1.f/(1.f+expf(-v)); }

__device__ __forceinline__ unsigned short f2bf(float f){
  unsigned u = __float_as_uint(f);
  return (unsigned short)((u + 0x7FFFu + ((u>>16)&1u)) >> 16);
}

// ---------------- weight cast (f32 -> bf16, RNE) ----------------
__global__ __launch_bounds__(256) void castw_kernel(const float* __restrict__ w,
    unsigned short* __restrict__ o, int n4)
{
  int i = blockIdx.x*256 + threadIdx.x;
  if (i < n4) {
    float4 v = ((const float4*)w)[i];
    ushort4 u;
    u.x = f2bf(v.x); u.y = f2bf(v.y); u.z = f2bf(v.z); u.w = f2bf(v.w);
    ((ushort4*)o)[i] = u;
  }
}

// ---------------- elementwise ----------------
__global__ __launch_bounds__(256) void delta_kernel(const float* __restrict__ x,
    const float* __restrict__ ts, float* __restrict__ delta,
    unsigned short* __restrict__ delta16)
{
  size_t i = (size_t)blockIdx.x*256 + threadIdx.x;
  int d = (int)(i & (DM-1));
  int r = (int)(i >> 9);
  int b = r / (TT-1), ii = r % (TT-1);
  float dt = ts[b*TT+ii+1] - ts[b*TT+ii];
  float x1 = x[((size_t)b*TT+ii+1)*DM + d];
  float x0 = x[((size_t)b*TT+ii)*DM + d];
  float v = (x1 - x0) / dt;
  delta[i] = v;
  delta16[i] = f2bf(v);
}

template<int INIT, int WRITE_Y>
__global__ __launch_bounds__(256) void rk_kernel(float* __restrict__ acc,
    unsigned short* y16, const float* __restrict__ delta,
    const float* __restrict__ f, const float* __restrict__ ts,
    float wa, float cy)
{
  size_t i = (size_t)blockIdx.x*256 + threadIdx.x;
  int r = (int)(i >> 9);
  int b = r / (TT-1), ii = r % (TT-1);
  float fv = f[i];
  float a = INIT ? 0.f : acc[i];
  acc[i] = a + wa*fv;
  if (WRITE_Y) {
    float dt = ts[b*TT+ii+1] - ts[b*TT+ii];
    y16[i] = f2bf(delta[i] + cy*dt*fv);
  }
}

__global__ __launch_bounds__(256) void states_kernel(const float* __restrict__ x,
    const float* __restrict__ ts, const float* __restrict__ acc,
    unsigned short* __restrict__ hin16)
{
  size_t i = (size_t)blockIdx.x*256 + threadIdx.x;
  int d = (int)(i & (DM-1));
  int r = (int)(i >> 9);
  int b = r >> 10, t = r & (TT-1);
  float v = 0.f;
  if (t > 0) {
    int ii = t-1;
    float dt = ts[b*TT+ii+1] - ts[b*TT+ii];
    v = x[((size_t)b*TT+ii)*DM + d] + dt*(1.f/6.f)*acc[((size_t)b*(TT-1)+ii)*DM + d];
  }
  hin16[i] = f2bf(v);
}

__global__ __launch_bounds__(256) void timeenc_kernel(const float* __restrict__ x,
    const float* __restrict__ ts, const float* __restrict__ te_a,
    const float* __restrict__ te_b, float* __restrict__ z)
{
  size_t i = (size_t)blockIdx.x*256 + threadIdx.x;
  int d = (int)(i & (DM-1));
  int r = (int)(i >> 9);
  float t = ts[r];
  float tm;
  if (d & 1) {
    int j = d >> 1;
    tm = t*te_a[j] + te_b[j];
  } else {
    int fi = d >> 2;
    float fr = expf(-(float)fi * 0.061606661f) * 1.5707964f;
    float ph = t * fr;
    tm = ((d & 3) == 0) ? sinf(ph) : cosf(ph);
  }
  z[i] = x[i] + tm;
}

// ---------------- LayerNorm (block per row, D=512) ----------------
template<int BF>   // 1: bf16 out, 0: f32 out
__global__ __launch_bounds__(256) void ln_kernel(const float* __restrict__ x,
    const float* __restrict__ w, const float* __restrict__ b,
    void* __restrict__ outp)
{
  int row = blockIdx.x;
  int tid = threadIdx.x;
  const float* xr = x + (size_t)row*DM;
  float2 v = *(const float2*)(xr + tid*2);
  float s = v.x+v.y, sq = v.x*v.x + v.y*v.y;
  #pragma unroll
  for (int off=1; off<64; off<<=1){ s += __shfl_xor(s,off); sq += __shfl_xor(sq,off); }
  __shared__ float rs[4], rq[4];
  int wid = tid>>6;
  if ((tid&63)==0){ rs[wid]=s; rq[wid]=sq; }
  __syncthreads();
  s = rs[0]+rs[1]+rs[2]+rs[3];
  sq = rq[0]+rq[1]+rq[2]+rq[3];
  float mean = s*(1.f/DM);
  float var = sq*(1.f/DM) - mean*mean;
  float inv = rsqrtf(var + 1e-5f);
  float2 wv = *(const float2*)(w + tid*2);
  float2 bv = *(const float2*)(b + tid*2);
  float ox = (v.x-mean)*inv*wv.x + bv.x;
  float oy = (v.y-mean)*inv*wv.y + bv.y;
  if (BF) {
    ushort2 u; u.x = f2bf(ox); u.y = f2bf(oy);
    *(ushort2*)((unsigned short*)outp + (size_t)row*DM + tid*2) = u;
  } else {
    float2 o; o.x = ox; o.y = oy;
    *(float2*)((float*)outp + (size_t)row*DM + tid*2) = o;
  }
}

// ---------------- bf16 MFMA GEMM: out = act(A16 @ Wb^T + bias) (+res) ----------------
// A16: MxK bf16 row-major. Wb: NxK bf16. 128x128 tile, BK=32, 4 waves 64x64 (4x4 frags).
// C (f32) and Cb (bf16) each nullable.
template<int ACT>  // 0 none, 1 relu, 2 tanh
__global__ __launch_bounds__(256) void bgemm_kernel(
    const unsigned short* __restrict__ A16, const unsigned short* __restrict__ Wb,
    const float* __restrict__ bias, const float* res,
    float* C, unsigned short* Cb, int M, int N, int K, int ldc)
{
  __shared__ __align__(16) unsigned short Al[2][128][40];
  __shared__ __align__(16) unsigned short Wl[2][128][40];
  const int bm = blockIdx.y*128, bn = blockIdx.x*128;
  const int tid = threadIdx.x;
  const int lane = tid & 63, wid = tid >> 6;
  const int wm = (wid&1)*64, wn = (wid>>1)*64;
  const int fl = lane & 15, fk = (lane>>4)*8;
  const int sar = tid>>2, sac = (tid&3)*8;      // A/W staging: row, 8-bf16 group
  f32x4 acc[4][4];
  #pragma unroll
  for (int i=0;i<4;i++)
    #pragma unroll
    for (int j=0;j<4;j++) acc[i][j] = (f32x4){0.f,0.f,0.f,0.f};

  uint4 areg[2], wreg[2];
  const int nk = K >> 5;

  auto load_t = [&](int kt){
    int k0 = kt*32;
    #pragma unroll
    for (int r=0;r<2;r++){
      int gr = bm + sar + r*64;
      areg[r] = (gr < M) ? *(const uint4*)(A16 + (size_t)gr*K + k0 + sac)
                         : make_uint4(0u,0u,0u,0u);
      wreg[r] = *(const uint4*)(Wb + (size_t)(bn + sar + r*64)*K + k0 + sac);
    }
  };
  auto store_t = [&](int buf){
    #pragma unroll
    for (int r=0;r<2;r++){
      *(uint4*)&Al[buf][sar + r*64][sac] = areg[r];
      *(uint4*)&Wl[buf][sar + r*64][sac] = wreg[r];
    }
  };

  load_t(0); store_t(0);
  int buf = 0;
  for (int kt = 0; kt < nk; ++kt) {
    __syncthreads();
    if (kt+1 < nk) load_t(kt+1);
    bf16x8 av[4], wv[4];
    #pragma unroll
    for (int i=0;i<4;i++) av[i] = *(const bf16x8*)&Al[buf][wm + i*16 + fl][fk];
    #pragma unroll
    for (int j=0;j<4;j++) wv[j] = *(const bf16x8*)&Wl[buf][wn + j*16 + fl][fk];
    #pragma unroll
    for (int i=0;i<4;i++)
      #pragma unroll
      for (int j=0;j<4;j++)
        acc[i][j] = __builtin_amdgcn_mfma_f32_16x16x32_bf16(av[i], wv[j], acc[i][j], 0, 0, 0);
    if (kt+1 < nk) store_t(buf^1);
    buf ^= 1;
  }

  // epilogue: C/D layout col=lane&15, row=(lane>>4)*4+reg
  #pragma unroll
  for (int j=0;j<4;j++){
    int gn = bn + wn + j*16 + fl;
    float bv = bias[gn];
    #pragma unroll
    for (int i=0;i<4;i++){
      #pragma unroll
      for (int r=0;r<4;r++){
        int gm = bm + wm + i*16 + (lane>>4)*4 + r;
        if (gm >= M) continue;
        float v = acc[i][j][r] + bv;
        if (ACT==1) v = fmaxf(v, 0.f);
        if (ACT==2) v = tanhf(v);
        if (res) v += res[(size_t)gm*ldc + gn];
        if (C)  C[(size_t)gm*ldc + gn] = v;
        if (Cb) Cb[(size_t)gm*ldc + gn] = f2bf(v);
      }
    }
  }
}

// ---------------- attention (f32 QKV in, bf16 O out) ----------------
template<int CAUSAL>
__global__ __launch_bounds__(256) void attn_kernel(const float* __restrict__ QKV,
                                                   unsigned short* __restrict__ O)
{
  __shared__ float qt[8][68];
  __shared__ float kt[32][68];
  __shared__ float vt[32][68];
  __shared__ float sc[8][1028];
  const int bh = blockIdx.x;
  const int b = bh >> 3, h = bh & 7;
  const int q0 = blockIdx.y * 8;
  const int tid = threadIdx.x;
  const int qrow = tid >> 5;
  const int klane = tid & 31;
  const float* base = QKV + (size_t)b*TT*1536;
  for (int idx = tid; idx < 8*64; idx += 256) {
    int q = idx >> 6, d = idx & 63;
    qt[q][d] = base[(size_t)(q0+q)*1536 + h*64 + d];
  }
  const int nkt = CAUSAL ? (q0/32 + 1) : (TT/32);
  for (int t0 = 0; t0 < nkt; t0++) {
    __syncthreads();
    for (int idx = tid; idx < 32*64; idx += 256) {
      int kk = idx >> 6, d = idx & 63;
      kt[kk][d] = base[(size_t)(t0*32+kk)*1536 + 512 + h*64 + d];
    }
    __syncthreads();
    float s = 0.f;
    #pragma unroll
    for (int d = 0; d < 64; d += 4) {
      float4 qv = *(const float4*)&qt[qrow][d];
      float4 kv = *(const float4*)&kt[klane][d];
      s += qv.x*kv.x + qv.y*kv.y + qv.z*kv.z + qv.w*kv.w;
    }
    int kg = t0*32 + klane;
    s *= 0.125f;
    if (CAUSAL && kg > q0 + qrow) s = -1e30f;
    sc[qrow][kg] = s;
  }
  __syncthreads();
  const int nk = nkt*32;
  float mx = -1e30f;
  for (int k = klane; k < nk; k += 32) mx = fmaxf(mx, sc[qrow][k]);
  #pragma unroll
  for (int off=1; off<32; off<<=1) mx = fmaxf(mx, __shfl_xor(mx, off));
  float sum = 0.f;
  for (int k = klane; k < nk; k += 32) { float e = expf(sc[qrow][k]-mx); sc[qrow][k]=e; sum += e; }
  #pragma unroll
  for (int off=1; off<32; off<<=1) sum += __shfl_xor(sum, off);
  float inv = 1.f/sum;
  for (int k = klane; k < nk; k += 32) sc[qrow][k] *= inv;
  float o0=0.f, o1=0.f;
  for (int t0 = 0; t0 < nkt; t0++) {
    __syncthreads();
    for (int idx = tid; idx < 32*64; idx += 256) {
      int kk = idx >> 6, d = idx & 63;
      vt[kk][d] = base[(size_t)(t0*32+kk)*1536 + 1024 + h*64 + d];
    }
    __syncthreads();
    #pragma unroll
    for (int kk=0; kk<32; kk++) {
      float p = sc[qrow][t0*32+kk];
      o0 += p*vt[kk][klane];
      o1 += p*vt[kk][klane+32];
    }
  }
  unsigned short* op = O + (size_t)(b*TT + q0 + qrow)*DM + h*64 + klane;
  op[0]  = f2bf(o0);
  op[32] = f2bf(o1);
}

// ---------------- GRU scan v4: tagged-value sync, zero fences, zero flags ----------------
// 512 blocks = 8 batches x 64 slices of 8 dims. Cross-block h travels as
// (float,tag) packed in one 64-bit word stored/loaded with RELAXED agent-scope
// atomics: the poll IS the data load (one MALL round trip per step).
// tag = t+1 (never 0 -> zero/poison init can't alias). Two buffers by t parity;
// pipeline dependency chain guarantees no overwrite-before-read.
// Compute: half-wave (32 lanes) per dim-row, consecutive float4 reads (no bank
// conflicts), shfl reduce, lane-0 finalize (no LDS reduction round trip).
__global__ __launch_bounds__(256) void gru_scan_kernel(
    const float* __restrict__ gx,   // (B*T,1536) includes bih
    const float* __restrict__ whh,  // (1536,512)
    const float* __restrict__ bhh,  // (1536)
    float* __restrict__ Hs,         // (B*T,512) f32
    unsigned short* __restrict__ Hsb, // bf16 shadow
    unsigned long long* hbuf)       // [2][BB][512] tagged
{
  __shared__ float wlds[3][GRU_J][512];
  __shared__ float hsp[512];
  const int blk = blockIdx.x;
  const int b = blk & 7;           // batch -> XCD (round-robin dispatch)
  const int g = blk >> 3;          // slice
  const int j0 = g * GRU_J;
  const int tid = threadIdx.x;

  for (int idx = tid; idx < 3*GRU_J*512/4; idx += 256) {
    int f = idx*4;
    int gate = f >> 12;
    int rem = f & 4095;
    int jj = rem >> 9, k = rem & 511;
    *(float4*)&wlds[gate][jj][k] = *(const float4*)&whh[(size_t)(gate*512 + j0 + jj)*512 + k];
  }
  const int row = tid >> 5;        // dim 0..7 (one per half-wave)
  const int kl = tid & 31;
  const bool fin = (kl == 0);
  float bh0=0.f, bh1=0.f, bh2=0.f;
  if (fin) { bh0 = bhh[j0+row]; bh1 = bhh[512+j0+row]; bh2 = bhh[1024+j0+row]; }
  __syncthreads();

  for (int t = 0; t < TT; t++) {
    float g0=0.f, g1=0.f, g2=0.f;
    if (fin) {   // issued before poll; latency hides under the wait
      const float* gxr = gx + ((size_t)b*TT + t)*1536 + j0 + row;
      g0 = gxr[0]; g1 = gxr[512]; g2 = gxr[1024];
    }
    if (t == 0) {
      hsp[tid] = 0.f; hsp[tid+256] = 0.f;
    } else {
      const unsigned want = (unsigned)t;   // tag of step t-1 output
      unsigned long long* src = hbuf + ((size_t)((t-1)&1)*BB + b)*512;
      unsigned long long u0, u1;
      for (;;) {
        u0 = __hip_atomic_load(&src[tid], __ATOMIC_RELAXED, __HIP_MEMORY_SCOPE_AGENT);
        if ((unsigned)(u0>>32) == want) break;
        __builtin_amdgcn_s_sleep(1);
      }
      for (;;) {
        u1 = __hip_atomic_load(&src[tid+256], __ATOMIC_RELAXED, __HIP_MEMORY_SCOPE_AGENT);
        if ((unsigned)(u1>>32) == want) break;
        __builtin_amdgcn_s_sleep(1);
      }
      hsp[tid]     = __uint_as_float((unsigned)u0);
      hsp[tid+256] = __uint_as_float((unsigned)u1);
    }
    __syncthreads();

    float s0=0.f, s1=0.f, s2=0.f;
    #pragma unroll
    for (int j=0;j<4;j++){
      int k = kl*4 + j*128;
      float4 h4 = *(const float4*)&hsp[k];
      float4 a = *(const float4*)&wlds[0][row][k];
      float4 c = *(const float4*)&wlds[1][row][k];
      float4 d = *(const float4*)&wlds[2][row][k];
      s0 += a.x*h4.x + a.y*h4.y + a.z*h4.z + a.w*h4.w;
      s1 += c.x*h4.x + c.y*h4.y + c.z*h4.z + c.w*h4.w;
      s2 += d.x*h4.x + d.y*h4.y + d.z*h4.z + d.w*h4.w;
    }
    #pragma unroll
    for (int off=1; off<32; off<<=1) {
      s0 += __shfl_xor(s0, off);
      s1 += __shfl_xor(s1, off);
      s2 += __shfl_xor(s2, off);
    }
    if (fin) {
      float r  = sigm_(g0 + s0 + bh0);
      float z  = sigm_(g1 + s1 + bh1);
      float n  = tanhf(g2 + r*(s2 + bh2));
      float hold = hsp[j0 + row];
      float hnew = (1.f - z)*n + z*hold;
      size_t o = ((size_t)b*TT + t)*DM + j0 + row;
      Hs[o]  = hnew;
      Hsb[o] = f2bf(hnew);
      unsigned long long pk = ((unsigned long long)(unsigned)(t+1) << 32) | __float_as_uint(hnew);
      __hip_atomic_store(&hbuf[((size_t)(t&1)*BB + b)*512 + j0 + row], pk,
                         __ATOMIC_RELAXED, __HIP_MEMORY_SCOPE_AGENT);
    }
    __syncthreads();
  }
}

// ---------------- host ----------------
static void launch_bgemm(int act, const unsigned short* A16, const unsigned short* Wb,
                         const float* bias, const float* res, float* C, unsigned short* Cb,
                         int M, int N, int K, int ldc, hipStream_t stream)
{
  dim3 grid(N/128, (M+127)/128), blk(256);
  switch(act){
    case 1: bgemm_kernel<1><<<grid,blk,0,stream>>>(A16,Wb,bias,res,C,Cb,M,N,K,ldc); break;
    case 2: bgemm_kernel<2><<<grid,blk,0,stream>>>(A16,Wb,bias,res,C,Cb,M,N,K,ldc); break;
    default: bgemm_kernel<0><<<grid,blk,0,stream>>>(A16,Wb,bias,res,C,Cb,M,N,K,ldc); break;
  }
}

static unsigned short* cast_w(const float* w, unsigned short* dst, size_t n, hipStream_t s)
{
  castw_kernel<<<((int)(n/4)+255)/256, 256, 0, s>>>(w, dst, (int)(n/4));
  return dst + n;
}

extern "C" void kernel_launch(void* const* d_in, const int* in_sizes, int n_in,
                              void* d_out, int out_size, void* d_ws, size_t ws_size,
                              hipStream_t stream)
{
  (void)in_sizes; (void)n_in; (void)out_size; (void)ws_size;
  const float* x       = (const float*)d_in[0];
  const float* ts      = (const float*)d_in[1];
  const float* ode_w1  = (const float*)d_in[2];
  const float* ode_b1  = (const float*)d_in[3];
  const float* ode_w2  = (const float*)d_in[4];
  const float* ode_b2  = (const float*)d_in[5];
  const float* gru_wih = (const float*)d_in[6];
  const float* gru_whh = (const float*)d_in[7];
  const float* gru_bih = (const float*)d_in[8];
  const float* gru_bhh = (const float*)d_in[9];
  const float* te_a    = (const float*)d_in[10];
  const float* te_b    = (const float*)d_in[11];
  const float* t_in_w  = (const float*)d_in[12];
  const float* t_in_b  = (const float*)d_in[13];
  const float* t_out_w = (const float*)d_in[14];
  const float* t_out_b = (const float*)d_in[15];
  const float* t_ln1_w = (const float*)d_in[16];
  const float* t_ln1_b = (const float*)d_in[17];
  const float* t_ln2_w = (const float*)d_in[18];
  const float* t_ln2_b = (const float*)d_in[19];
  const float* t_ff1_w = (const float*)d_in[20];
  const float* t_ff1_b = (const float*)d_in[21];
  const float* t_ff2_w = (const float*)d_in[22];
  const float* t_ff2_b = (const float*)d_in[23];
  const float* t_lnf_w = (const float*)d_in[24];
  const float* t_lnf_b = (const float*)d_in[25];
  const float* ca_in_w = (const float*)d_in[26];
  const float* ca_in_b = (const float*)d_in[27];
  const float* ca_out_w= (const float*)d_in[28];
  const float* ca_out_b= (const float*)d_in[29];
  const float* ca_lin_w= (const float*)d_in[30];
  const float* ca_lin_b= (const float*)d_in[31];
  const float* ca_ln_w = (const float*)d_in[32];
  const float* ca_ln_b = (const float*)d_in[33];

  float* ws = (float*)d_ws;
  const size_t SZ = (size_t)ROWS * DM;          // 4M elements
  // f32 pool
  float* deltab = ws + 0*SZ;
  float* accb   = ws + 1*SZ;
  float* fcur   = ws + 2*SZ;                    // ode f / later ca pre-LN
  float* qkv    = ws + 3*SZ;                    // 3*SZ: gx / QKV
  float* zbuf   = ws + 6*SZ;
  float* hsb    = ws + 7*SZ;                    // GRU H f32 (res for ca_lin)
  unsigned long long* hbuf = (unsigned long long*)(ws + 8*SZ);  // 64KB tagged h
  // bf16 pool
  unsigned short* u16 = (unsigned short*)(ws + 8*SZ + 16384);
  unsigned short* delta16 = u16 + 0*SZ;         // later: ao16
  unsigned short* y16     = u16 + 1*SZ;         // later: hin16, cao16
  unsigned short* t16     = u16 + 2*SZ;         // later: ln16
  unsigned short* hs16    = u16 + 3*SZ;         // GRU H bf16 (persists)
  unsigned short* ff1b16  = u16 + 4*SZ;         // 4*SZ: relu out (M x 2048)
  unsigned short* ao16    = delta16;
  unsigned short* hin16   = y16;
  unsigned short* cao16   = y16;
  unsigned short* ln16    = t16;
  // weights
  unsigned short* wp = u16 + 8*SZ;
  unsigned short* wb_ode1 = wp;  wp = cast_w(ode_w1,  wp, 512*512, stream);
  unsigned short* wb_ode2 = wp;  wp = cast_w(ode_w2,  wp, 512*512, stream);
  unsigned short* wb_gwih = wp;  wp = cast_w(gru_wih, wp, 1536*512, stream);
  unsigned short* wb_tin  = wp;  wp = cast_w(t_in_w,  wp, (size_t)2*1536*512, stream);
  unsigned short* wb_tout = wp;  wp = cast_w(t_out_w, wp, (size_t)2*512*512, stream);
  unsigned short* wb_ff1  = wp;  wp = cast_w(t_ff1_w, wp, (size_t)2*2048*512, stream);
  unsigned short* wb_ff2  = wp;  wp = cast_w(t_ff2_w, wp, (size_t)2*512*2048, stream);
  unsigned short* wb_cain = wp;  wp = cast_w(ca_in_w, wp, 1536*512, stream);
  unsigned short* wb_caout= wp;  wp = cast_w(ca_out_w,wp, 512*512, stream);
  unsigned short* wb_calin= wp;  wp = cast_w(ca_lin_w,wp, 512*512, stream);

  // ---- ODE (RK4) ----
  delta_kernel<<<ROWS1*DM/256, 256, 0, stream>>>(x, ts, deltab, delta16);
  const unsigned short* yin16 = delta16;
  const float was[4] = {1.f, 2.f, 2.f, 1.f};
  const float cys[4] = {0.5f, 0.5f, 1.f, 0.f};
  for (int s4 = 0; s4 < 4; s4++) {
    launch_bgemm(2, yin16, wb_ode1, ode_b1, nullptr, nullptr, t16, ROWS1, 512, 512, 512, stream);
    launch_bgemm(0, t16,  wb_ode2, ode_b2, nullptr, fcur, nullptr, ROWS1, 512, 512, 512, stream);
    if (s4 == 0)
      rk_kernel<1,1><<<ROWS1*DM/256,256,0,stream>>>(accb, y16, deltab, fcur, ts, was[s4], cys[s4]);
    else if (s4 < 3)
      rk_kernel<0,1><<<ROWS1*DM/256,256,0,stream>>>(accb, y16, deltab, fcur, ts, was[s4], cys[s4]);
    else
      rk_kernel<0,0><<<ROWS1*DM/256,256,0,stream>>>(accb, nullptr, deltab, fcur, ts, was[s4], 0.f);
    yin16 = y16;
  }
  states_kernel<<<ROWS*DM/256,256,0,stream>>>(x, ts, accb, hin16);

  // ---- GRU ----
  launch_bgemm(0, hin16, wb_gwih, gru_bih, nullptr, qkv, nullptr, ROWS, 1536, 512, 1536, stream);
  gru_scan_kernel<<<GRU_BLK, 256, 0, stream>>>(qkv, gru_whh, gru_bhh, hsb, hs16, hbuf);

  // ---- time encoding ----
  timeenc_kernel<<<ROWS*DM/256,256,0,stream>>>(x, ts, te_a, te_b, zbuf);

  // ---- transformer (2 layers, pre-norm, causal) ----
  for (int l = 0; l < 2; l++) {
    ln_kernel<1><<<ROWS,256,0,stream>>>(zbuf, t_ln1_w + l*512, t_ln1_b + l*512, ln16);
    launch_bgemm(0, ln16, wb_tin + (size_t)l*1536*512, t_in_b + l*1536, nullptr, qkv, nullptr, ROWS, 1536, 512, 1536, stream);
    attn_kernel<1><<<dim3(64, TT/8), 256, 0, stream>>>(qkv, ao16);
    launch_bgemm(0, ao16, wb_tout + (size_t)l*512*512, t_out_b + l*512, zbuf, zbuf, nullptr, ROWS, 512, 512, 512, stream);
    ln_kernel<1><<<ROWS,256,0,stream>>>(zbuf, t_ln2_w + l*512, t_ln2_b + l*512, ln16);
    launch_bgemm(1, ln16, wb_ff1 + (size_t)l*2048*512, t_ff1_b + l*2048, nullptr, nullptr, ff1b16, ROWS, 2048, 512, 2048, stream);
    launch_bgemm(0, ff1b16, wb_ff2 + (size_t)l*512*2048, t_ff2_b + l*512, zbuf, zbuf, nullptr, ROWS, 512, 2048, 512, stream);
  }
  ln_kernel<1><<<ROWS,256,0,stream>>>(zbuf, t_lnf_w, t_lnf_b, ln16);  // zf bf16

  // ---- cross attention: Q from Hs, K/V from zf ----
  launch_bgemm(0, hs16, wb_cain,           ca_in_b,       nullptr, qkv,       nullptr, ROWS,  512, 512, 1536, stream);
  launch_bgemm(0, ln16, wb_cain + 512*512, ca_in_b + 512, nullptr, qkv + 512, nullptr, ROWS, 1024, 512, 1536, stream);
  attn_kernel<0><<<dim3(64, TT/8), 256, 0, stream>>>(qkv, ao16);
  launch_bgemm(0, ao16, wb_caout, ca_out_b, nullptr, nullptr, cao16, ROWS, 512, 512, 512, stream);
  launch_bgemm(0, cao16, wb_calin, ca_lin_b, hsb, fcur, nullptr, ROWS, 512, 512, 512, stream);
  ln_kernel<0><<<ROWS,256,0,stream>>>(fcur, ca_ln_w, ca_ln_b, (float*)d_out);
}

// Round 6
// 3197.402 us; speedup vs baseline: 5.1025x; 1.7689x over previous
//
#include <hip/hip_runtime.h>
#include <math.h>

#define BB 8
#define TT 1024
#define DM 512
#define ROWS (BB*TT)     // 8192
#define ROWS1 (BB*(TT-1))// 8184
#define GRU_J 8
#define GRU_BLK (BB*64)  // 512 blocks

typedef __attribute__((ext_vector_type(4))) float f32x4;
typedef __attribute__((ext_vector_type(8))) short bf16x8;
typedef __attribute__((ext_vector_type(4))) short bf16x4;

__device__ __forceinline__ float sigm_(float v){ return 1.f/(1.f+expf(-v)); }

__device__ __forceinline__ unsigned short f2bf(float f){
  unsigned u = __float_as_uint(f);
  return (unsigned short)((u + 0x7FFFu + ((u>>16)&1u)) >> 16);
}

// ---------------- weight cast (f32 -> bf16, RNE) ----------------
__global__ __launch_bounds__(256) void castw_kernel(const float* __restrict__ w,
    unsigned short* __restrict__ o, int n4)
{
  int i = blockIdx.x*256 + threadIdx.x;
  if (i < n4) {
    float4 v = ((const float4*)w)[i];
    ushort4 u;
    u.x = f2bf(v.x); u.y = f2bf(v.y); u.z = f2bf(v.z); u.w = f2bf(v.w);
    ((ushort4*)o)[i] = u;
  }
}

// ---------------- elementwise ----------------
__global__ __launch_bounds__(256) void delta_kernel(const float* __restrict__ x,
    const float* __restrict__ ts, float* __restrict__ delta,
    unsigned short* __restrict__ delta16)
{
  size_t i = (size_t)blockIdx.x*256 + threadIdx.x;
  int d = (int)(i & (DM-1));
  int r = (int)(i >> 9);
  int b = r / (TT-1), ii = r % (TT-1);
  float dt = ts[b*TT+ii+1] - ts[b*TT+ii];
  float x1 = x[((size_t)b*TT+ii+1)*DM + d];
  float x0 = x[((size_t)b*TT+ii)*DM + d];
  float v = (x1 - x0) / dt;
  delta[i] = v;
  delta16[i] = f2bf(v);
}

template<int INIT, int WRITE_Y>
__global__ __launch_bounds__(256) void rk_kernel(float* __restrict__ acc,
    unsigned short* y16, const float* __restrict__ delta,
    const float* __restrict__ f, const float* __restrict__ ts,
    float wa, float cy)
{
  size_t i = (size_t)blockIdx.x*256 + threadIdx.x;
  int r = (int)(i >> 9);
  int b = r / (TT-1), ii = r % (TT-1);
  float fv = f[i];
  float a = INIT ? 0.f : acc[i];
  acc[i] = a + wa*fv;
  if (WRITE_Y) {
    float dt = ts[b*TT+ii+1] - ts[b*TT+ii];
    y16[i] = f2bf(delta[i] + cy*dt*fv);
  }
}

__global__ __launch_bounds__(256) void states_kernel(const float* __restrict__ x,
    const float* __restrict__ ts, const float* __restrict__ acc,
    unsigned short* __restrict__ hin16)
{
  size_t i = (size_t)blockIdx.x*256 + threadIdx.x;
  int d = (int)(i & (DM-1));
  int r = (int)(i >> 9);
  int b = r >> 10, t = r & (TT-1);
  float v = 0.f;
  if (t > 0) {
    int ii = t-1;
    float dt = ts[b*TT+ii+1] - ts[b*TT+ii];
    v = x[((size_t)b*TT+ii)*DM + d] + dt*(1.f/6.f)*acc[((size_t)b*(TT-1)+ii)*DM + d];
  }
  hin16[i] = f2bf(v);
}

__global__ __launch_bounds__(256) void timeenc_kernel(const float* __restrict__ x,
    const float* __restrict__ ts, const float* __restrict__ te_a,
    const float* __restrict__ te_b, float* __restrict__ z)
{
  size_t i = (size_t)blockIdx.x*256 + threadIdx.x;
  int d = (int)(i & (DM-1));
  int r = (int)(i >> 9);
  float t = ts[r];
  float tm;
  if (d & 1) {
    int j = d >> 1;
    tm = t*te_a[j] + te_b[j];
  } else {
    int fi = d >> 2;
    float fr = expf(-(float)fi * 0.061606661f) * 1.5707964f;
    float ph = t * fr;
    tm = ((d & 3) == 0) ? sinf(ph) : cosf(ph);
  }
  z[i] = x[i] + tm;
}

// ---------------- LayerNorm (block per row, D=512) ----------------
template<int BF>
__global__ __launch_bounds__(256) void ln_kernel(const float* __restrict__ x,
    const float* __restrict__ w, const float* __restrict__ b,
    void* __restrict__ outp)
{
  int row = blockIdx.x;
  int tid = threadIdx.x;
  const float* xr = x + (size_t)row*DM;
  float2 v = *(const float2*)(xr + tid*2);
  float s = v.x+v.y, sq = v.x*v.x + v.y*v.y;
  #pragma unroll
  for (int off=1; off<64; off<<=1){ s += __shfl_xor(s,off); sq += __shfl_xor(sq,off); }
  __shared__ float rs[4], rq[4];
  int wid = tid>>6;
  if ((tid&63)==0){ rs[wid]=s; rq[wid]=sq; }
  __syncthreads();
  s = rs[0]+rs[1]+rs[2]+rs[3];
  sq = rq[0]+rq[1]+rq[2]+rq[3];
  float mean = s*(1.f/DM);
  float var = sq*(1.f/DM) - mean*mean;
  float inv = rsqrtf(var + 1e-5f);
  float2 wv = *(const float2*)(w + tid*2);
  float2 bv = *(const float2*)(b + tid*2);
  float ox = (v.x-mean)*inv*wv.x + bv.x;
  float oy = (v.y-mean)*inv*wv.y + bv.y;
  if (BF) {
    ushort2 u; u.x = f2bf(ox); u.y = f2bf(oy);
    *(ushort2*)((unsigned short*)outp + (size_t)row*DM + tid*2) = u;
  } else {
    float2 o; o.x = ox; o.y = oy;
    *(float2*)((float*)outp + (size_t)row*DM + tid*2) = o;
  }
}

// ---------------- bf16 MFMA GEMM ----------------
template<int ACT>
__global__ __launch_bounds__(256) void bgemm_kernel(
    const unsigned short* __restrict__ A16, const unsigned short* __restrict__ Wb,
    const float* __restrict__ bias, const float* res,
    float* C, unsigned short* Cb, int M, int N, int K, int ldc)
{
  __shared__ __align__(16) unsigned short Al[2][128][40];
  __shared__ __align__(16) unsigned short Wl[2][128][40];
  const int bm = blockIdx.y*128, bn = blockIdx.x*128;
  const int tid = threadIdx.x;
  const int lane = tid & 63, wid = tid >> 6;
  const int wm = (wid&1)*64, wn = (wid>>1)*64;
  const int fl = lane & 15, fk = (lane>>4)*8;
  const int sar = tid>>2, sac = (tid&3)*8;
  f32x4 acc[4][4];
  #pragma unroll
  for (int i=0;i<4;i++)
    #pragma unroll
    for (int j=0;j<4;j++) acc[i][j] = (f32x4){0.f,0.f,0.f,0.f};

  uint4 areg[2], wreg[2];
  const int nk = K >> 5;

  auto load_t = [&](int kt){
    int k0 = kt*32;
    #pragma unroll
    for (int r=0;r<2;r++){
      int gr = bm + sar + r*64;
      areg[r] = (gr < M) ? *(const uint4*)(A16 + (size_t)gr*K + k0 + sac)
                         : make_uint4(0u,0u,0u,0u);
      wreg[r] = *(const uint4*)(Wb + (size_t)(bn + sar + r*64)*K + k0 + sac);
    }
  };
  auto store_t = [&](int buf){
    #pragma unroll
    for (int r=0;r<2;r++){
      *(uint4*)&Al[buf][sar + r*64][sac] = areg[r];
      *(uint4*)&Wl[buf][sar + r*64][sac] = wreg[r];
    }
  };

  load_t(0); store_t(0);
  int buf = 0;
  for (int kt = 0; kt < nk; ++kt) {
    __syncthreads();
    if (kt+1 < nk) load_t(kt+1);
    bf16x8 av[4], wv[4];
    #pragma unroll
    for (int i=0;i<4;i++) av[i] = *(const bf16x8*)&Al[buf][wm + i*16 + fl][fk];
    #pragma unroll
    for (int j=0;j<4;j++) wv[j] = *(const bf16x8*)&Wl[buf][wn + j*16 + fl][fk];
    #pragma unroll
    for (int i=0;i<4;i++)
      #pragma unroll
      for (int j=0;j<4;j++)
        acc[i][j] = __builtin_amdgcn_mfma_f32_16x16x32_bf16(av[i], wv[j], acc[i][j], 0, 0, 0);
    if (kt+1 < nk) store_t(buf^1);
    buf ^= 1;
  }

  #pragma unroll
  for (int j=0;j<4;j++){
    int gn = bn + wn + j*16 + fl;
    float bv = bias[gn];
    #pragma unroll
    for (int i=0;i<4;i++){
      #pragma unroll
      for (int r=0;r<4;r++){
        int gm = bm + wm + i*16 + (lane>>4)*4 + r;
        if (gm >= M) continue;
        float v = acc[i][j][r] + bv;
        if (ACT==1) v = fmaxf(v, 0.f);
        if (ACT==2) v = tanhf(v);
        if (res) v += res[(size_t)gm*ldc + gn];
        if (C)  C[(size_t)gm*ldc + gn] = v;
        if (Cb) Cb[(size_t)gm*ldc + gn] = f2bf(v);
      }
    }
  }
}

// ---------------- MFMA flash attention ----------------
// QKV bf16 (B*T,1536): Q cols [0,512), K [512,1024), V [1024,1536); 8 heads x 64.
// Block: one (b,h), 64 q rows (4 waves x 16). Online softmax, K staged in LDS,
// V staged transposed, Q held in per-lane A-frag registers, P via per-wave LDS.
template<int CAUSAL>
__global__ __launch_bounds__(256) void mattn_kernel(
    const unsigned short* __restrict__ QKV, unsigned short* __restrict__ O)
{
  __shared__ __align__(16) unsigned short Kl[32][72];
  __shared__ __align__(16) unsigned short Vt[64][36];
  __shared__ __align__(16) unsigned short Pl[4][16][40];
  const int b = blockIdx.x >> 3, h = blockIdx.x & 7;
  const int q0 = blockIdx.y * 64;
  const int tid = threadIdx.x;
  const int lane = tid & 63, wid = tid >> 6;
  const int lq = lane & 15, g = lane >> 4;
  const size_t rowbase = (size_t)b*TT;

  bf16x8 qf0, qf1;
  {
    const unsigned short* qp = QKV + (rowbase + q0 + wid*16 + lq)*1536 + h*64 + g*8;
    qf0 = *(const bf16x8*)qp;
    qf1 = *(const bf16x8*)(qp + 32);
  }
  f32x4 o[4];
  #pragma unroll
  for (int dt=0; dt<4; dt++) o[dt] = (f32x4){0.f,0.f,0.f,0.f};
  float mr[4] = {-1e30f,-1e30f,-1e30f,-1e30f};
  float Lr[4] = {0.f,0.f,0.f,0.f};

  const int nkt = CAUSAL ? (q0/32 + 2) : (TT/32);
  const int qwmax = q0 + wid*16 + 15;
  const int sr = tid >> 3, scol = (tid & 7) * 8;

  for (int kt = 0; kt < nkt; ++kt) {
    const int k0 = kt*32;
    __syncthreads();
    *(uint4*)&Kl[sr][scol] = *(const uint4*)(QKV + (rowbase + k0 + sr)*1536 + 512 + h*64 + scol);
    {
      uint4 vv = *(const uint4*)(QKV + (rowbase + k0 + sr)*1536 + 1024 + h*64 + scol);
      const unsigned short* vs = (const unsigned short*)&vv;
      #pragma unroll
      for (int i=0;i<8;i++) Vt[scol+i][sr] = vs[i];
    }
    __syncthreads();
    if (CAUSAL && k0 > qwmax) continue;   // whole wave skips; barriers already hit

    // S = Q @ K^T   (D: row q_local=4g+r, col k_local=lq)
    f32x4 st0 = (f32x4){0.f,0.f,0.f,0.f}, st1 = (f32x4){0.f,0.f,0.f,0.f};
    {
      bf16x8 kb;
      kb = *(const bf16x8*)&Kl[lq][g*8];
      st0 = __builtin_amdgcn_mfma_f32_16x16x32_bf16(qf0, kb, st0, 0,0,0);
      kb = *(const bf16x8*)&Kl[lq][g*8+32];
      st0 = __builtin_amdgcn_mfma_f32_16x16x32_bf16(qf1, kb, st0, 0,0,0);
      kb = *(const bf16x8*)&Kl[16+lq][g*8];
      st1 = __builtin_amdgcn_mfma_f32_16x16x32_bf16(qf0, kb, st1, 0,0,0);
      kb = *(const bf16x8*)&Kl[16+lq][g*8+32];
      st1 = __builtin_amdgcn_mfma_f32_16x16x32_bf16(qf1, kb, st1, 0,0,0);
    }
    float s0[4], s1[4];
    #pragma unroll
    for (int r=0;r<4;r++){ s0[r] = st0[r]*0.125f; s1[r] = st1[r]*0.125f; }
    if (CAUSAL) {
      int kg0 = k0 + lq, kg1 = k0 + 16 + lq;
      #pragma unroll
      for (int r=0;r<4;r++){
        int qg = q0 + wid*16 + 4*g + r;
        if (kg0 > qg) s0[r] = -1e30f;
        if (kg1 > qg) s1[r] = -1e30f;
      }
    }
    #pragma unroll
    for (int r=0;r<4;r++){
      float v = fmaxf(s0[r], s1[r]);
      v = fmaxf(v, __shfl_xor(v,1));
      v = fmaxf(v, __shfl_xor(v,2));
      v = fmaxf(v, __shfl_xor(v,4));
      v = fmaxf(v, __shfl_xor(v,8));
      float mn = fmaxf(mr[r], v);
      float scl = expf(mr[r] - mn);
      mr[r] = mn;
      float p0 = expf(s0[r] - mn);
      float p1 = expf(s1[r] - mn);
      float lt = p0 + p1;
      lt += __shfl_xor(lt,1); lt += __shfl_xor(lt,2);
      lt += __shfl_xor(lt,4); lt += __shfl_xor(lt,8);
      Lr[r] = Lr[r]*scl + lt;
      o[0][r] *= scl; o[1][r] *= scl; o[2][r] *= scl; o[3][r] *= scl;
      Pl[wid][4*g+r][lq]    = f2bf(p0);
      Pl[wid][4*g+r][16+lq] = f2bf(p1);
    }
    // O += P @ V
    bf16x8 ap = *(const bf16x8*)&Pl[wid][lq][g*8];
    #pragma unroll
    for (int dt=0; dt<4; dt++){
      bf16x4 a4 = *(const bf16x4*)&Vt[lq+16*dt][g*8];
      bf16x4 b4 = *(const bf16x4*)&Vt[lq+16*dt][g*8+4];
      bf16x8 vb = __builtin_shufflevector(a4, b4, 0,1,2,3,4,5,6,7);
      o[dt] = __builtin_amdgcn_mfma_f32_16x16x32_bf16(ap, vb, o[dt], 0,0,0);
    }
  }

  #pragma unroll
  for (int r=0;r<4;r++){
    float inv = 1.f / Lr[r];
    int qg = q0 + wid*16 + 4*g + r;
    unsigned short* op = O + (rowbase + qg)*DM + h*64 + lq;
    op[0]  = f2bf(o[0][r]*inv);
    op[16] = f2bf(o[1][r]*inv);
    op[32] = f2bf(o[2][r]*inv);
    op[48] = f2bf(o[3][r]*inv);
  }
}

// ---------------- GRU scan v4.1: tagged-value sync, concurrent polls ----------------
__global__ __launch_bounds__(256) void gru_scan_kernel(
    const float* __restrict__ gx,
    const float* __restrict__ whh,
    const float* __restrict__ bhh,
    float* __restrict__ Hs,
    unsigned short* __restrict__ Hsb,
    unsigned long long* hbuf)
{
  __shared__ float wlds[3][GRU_J][512];
  __shared__ float hsp[512];
  const int blk = blockIdx.x;
  const int b = blk & 7;
  const int g = blk >> 3;
  const int j0 = g * GRU_J;
  const int tid = threadIdx.x;

  for (int idx = tid; idx < 3*GRU_J*512/4; idx += 256) {
    int f = idx*4;
    int gate = f >> 12;
    int rem = f & 4095;
    int jj = rem >> 9, k = rem & 511;
    *(float4*)&wlds[gate][jj][k] = *(const float4*)&whh[(size_t)(gate*512 + j0 + jj)*512 + k];
  }
  const int row = tid >> 5;
  const int kl = tid & 31;
  const bool fin = (kl == 0);
  float bh0=0.f, bh1=0.f, bh2=0.f;
  if (fin) { bh0 = bhh[j0+row]; bh1 = bhh[512+j0+row]; bh2 = bhh[1024+j0+row]; }
  __syncthreads();

  for (int t = 0; t < TT; t++) {
    float g0=0.f, g1=0.f, g2=0.f;
    if (fin) {
      const float* gxr = gx + ((size_t)b*TT + t)*1536 + j0 + row;
      g0 = gxr[0]; g1 = gxr[512]; g2 = gxr[1024];
    }
    if (t == 0) {
      hsp[tid] = 0.f; hsp[tid+256] = 0.f;
    } else {
      const unsigned want = (unsigned)t;
      unsigned long long* src = hbuf + ((size_t)((t-1)&1)*BB + b)*512;
      unsigned long long u0, u1;
      for (;;) {
        u0 = __hip_atomic_load(src + tid,       __ATOMIC_RELAXED, __HIP_MEMORY_SCOPE_AGENT);
        u1 = __hip_atomic_load(src + tid + 256, __ATOMIC_RELAXED, __HIP_MEMORY_SCOPE_AGENT);
        if (((unsigned)(u0>>32) == want) & ((unsigned)(u1>>32) == want)) break;
        __builtin_amdgcn_s_sleep(1);
      }
      hsp[tid]     = __uint_as_float((unsigned)u0);
      hsp[tid+256] = __uint_as_float((unsigned)u1);
    }
    __syncthreads();

    float s0=0.f, s1=0.f, s2=0.f;
    #pragma unroll
    for (int j=0;j<4;j++){
      int k = kl*4 + j*128;
      float4 h4 = *(const float4*)&hsp[k];
      float4 a = *(const float4*)&wlds[0][row][k];
      float4 c = *(const float4*)&wlds[1][row][k];
      float4 d = *(const float4*)&wlds[2][row][k];
      s0 += a.x*h4.x + a.y*h4.y + a.z*h4.z + a.w*h4.w;
      s1 += c.x*h4.x + c.y*h4.y + c.z*h4.z + c.w*h4.w;
      s2 += d.x*h4.x + d.y*h4.y + d.z*h4.z + d.w*h4.w;
    }
    #pragma unroll
    for (int off=1; off<32; off<<=1) {
      s0 += __shfl_xor(s0, off);
      s1 += __shfl_xor(s1, off);
      s2 += __shfl_xor(s2, off);
    }
    if (fin) {
      float r  = sigm_(g0 + s0 + bh0);
      float z  = sigm_(g1 + s1 + bh1);
      float n  = tanhf(g2 + r*(s2 + bh2));
      float hold = hsp[j0 + row];
      float hnew = (1.f - z)*n + z*hold;
      size_t off = ((size_t)b*TT + t)*DM + j0 + row;
      Hs[off]  = hnew;
      Hsb[off] = f2bf(hnew);
      unsigned long long pk = ((unsigned long long)(unsigned)(t+1) << 32) | __float_as_uint(hnew);
      __hip_atomic_store(&hbuf[((size_t)(t&1)*BB + b)*512 + j0 + row], pk,
                         __ATOMIC_RELAXED, __HIP_MEMORY_SCOPE_AGENT);
    }
    __syncthreads();
  }
}

// ---------------- host ----------------
static void launch_bgemm(int act, const unsigned short* A16, const unsigned short* Wb,
                         const float* bias, const float* res, float* C, unsigned short* Cb,
                         int M, int N, int K, int ldc, hipStream_t stream)
{
  dim3 grid(N/128, (M+127)/128), blk(256);
  switch(act){
    case 1: bgemm_kernel<1><<<grid,blk,0,stream>>>(A16,Wb,bias,res,C,Cb,M,N,K,ldc); break;
    case 2: bgemm_kernel<2><<<grid,blk,0,stream>>>(A16,Wb,bias,res,C,Cb,M,N,K,ldc); break;
    default: bgemm_kernel<0><<<grid,blk,0,stream>>>(A16,Wb,bias,res,C,Cb,M,N,K,ldc); break;
  }
}

static unsigned short* cast_w(const float* w, unsigned short* dst, size_t n, hipStream_t s)
{
  castw_kernel<<<((int)(n/4)+255)/256, 256, 0, s>>>(w, dst, (int)(n/4));
  return dst + n;
}

extern "C" void kernel_launch(void* const* d_in, const int* in_sizes, int n_in,
                              void* d_out, int out_size, void* d_ws, size_t ws_size,
                              hipStream_t stream)
{
  (void)in_sizes; (void)n_in; (void)out_size; (void)ws_size;
  const float* x       = (const float*)d_in[0];
  const float* ts      = (const float*)d_in[1];
  const float* ode_w1  = (const float*)d_in[2];
  const float* ode_b1  = (const float*)d_in[3];
  const float* ode_w2  = (const float*)d_in[4];
  const float* ode_b2  = (const float*)d_in[5];
  const float* gru_wih = (const float*)d_in[6];
  const float* gru_whh = (const float*)d_in[7];
  const float* gru_bih = (const float*)d_in[8];
  const float* gru_bhh = (const float*)d_in[9];
  const float* te_a    = (const float*)d_in[10];
  const float* te_b    = (const float*)d_in[11];
  const float* t_in_w  = (const float*)d_in[12];
  const float* t_in_b  = (const float*)d_in[13];
  const float* t_out_w = (const float*)d_in[14];
  const float* t_out_b = (const float*)d_in[15];
  const float* t_ln1_w = (const float*)d_in[16];
  const float* t_ln1_b = (const float*)d_in[17];
  const float* t_ln2_w = (const float*)d_in[18];
  const float* t_ln2_b = (const float*)d_in[19];
  const float* t_ff1_w = (const float*)d_in[20];
  const float* t_ff1_b = (const float*)d_in[21];
  const float* t_ff2_w = (const float*)d_in[22];
  const float* t_ff2_b = (const float*)d_in[23];
  const float* t_lnf_w = (const float*)d_in[24];
  const float* t_lnf_b = (const float*)d_in[25];
  const float* ca_in_w = (const float*)d_in[26];
  const float* ca_in_b = (const float*)d_in[27];
  const float* ca_out_w= (const float*)d_in[28];
  const float* ca_out_b= (const float*)d_in[29];
  const float* ca_lin_w= (const float*)d_in[30];
  const float* ca_lin_b= (const float*)d_in[31];
  const float* ca_ln_w = (const float*)d_in[32];
  const float* ca_ln_b = (const float*)d_in[33];

  float* ws = (float*)d_ws;
  const size_t SZ = (size_t)ROWS * DM;
  // f32 pool (8*SZ)
  float* deltab = ws + 0*SZ;
  float* accb   = ws + 1*SZ;
  float* fcur   = ws + 2*SZ;                 // ode f / later ca pre-LN
  float* gx     = ws + 3*SZ;                 // 3*SZ: GRU input proj (f32)
  float* zbuf   = ws + 6*SZ;
  float* hsb    = ws + 7*SZ;                 // GRU H f32 (res for ca_lin)
  unsigned long long* hbuf = (unsigned long long*)(ws + 8*SZ);  // 64KB
  // bf16 pool
  unsigned short* u16 = (unsigned short*)(ws + 8*SZ + 16384);
  unsigned short* delta16 = u16 + 0*SZ;      // later: ao16
  unsigned short* y16     = u16 + 1*SZ;      // later: hin16, cao16
  unsigned short* t16     = u16 + 2*SZ;      // later: ln16
  unsigned short* hs16    = u16 + 3*SZ;
  unsigned short* ff1b16  = u16 + 4*SZ;      // 4*SZ; qkv16 aliases here
  unsigned short* qkv16   = ff1b16;          // 3*SZ bf16 (B*T,1536)
  unsigned short* ao16    = delta16;
  unsigned short* hin16   = y16;
  unsigned short* cao16   = y16;
  unsigned short* ln16    = t16;
  // weights
  unsigned short* wp = u16 + 8*SZ;
  unsigned short* wb_ode1 = wp;  wp = cast_w(ode_w1,  wp, 512*512, stream);
  unsigned short* wb_ode2 = wp;  wp = cast_w(ode_w2,  wp, 512*512, stream);
  unsigned short* wb_gwih = wp;  wp = cast_w(gru_wih, wp, 1536*512, stream);
  unsigned short* wb_tin  = wp;  wp = cast_w(t_in_w,  wp, (size_t)2*1536*512, stream);
  unsigned short* wb_tout = wp;  wp = cast_w(t_out_w, wp, (size_t)2*512*512, stream);
  unsigned short* wb_ff1  = wp;  wp = cast_w(t_ff1_w, wp, (size_t)2*2048*512, stream);
  unsigned short* wb_ff2  = wp;  wp = cast_w(t_ff2_w, wp, (size_t)2*512*2048, stream);
  unsigned short* wb_cain = wp;  wp = cast_w(ca_in_w, wp, 1536*512, stream);
  unsigned short* wb_caout= wp;  wp = cast_w(ca_out_w,wp, 512*512, stream);
  unsigned short* wb_calin= wp;  wp = cast_w(ca_lin_w,wp, 512*512, stream);

  // ---- ODE (RK4) ----
  delta_kernel<<<ROWS1*DM/256, 256, 0, stream>>>(x, ts, deltab, delta16);
  const unsigned short* yin16 = delta16;
  const float was[4] = {1.f, 2.f, 2.f, 1.f};
  const float cys[4] = {0.5f, 0.5f, 1.f, 0.f};
  for (int s4 = 0; s4 < 4; s4++) {
    launch_bgemm(2, yin16, wb_ode1, ode_b1, nullptr, nullptr, t16, ROWS1, 512, 512, 512, stream);
    launch_bgemm(0, t16,  wb_ode2, ode_b2, nullptr, fcur, nullptr, ROWS1, 512, 512, 512, stream);
    if (s4 == 0)
      rk_kernel<1,1><<<ROWS1*DM/256,256,0,stream>>>(accb, y16, deltab, fcur, ts, was[s4], cys[s4]);
    else if (s4 < 3)
      rk_kernel<0,1><<<ROWS1*DM/256,256,0,stream>>>(accb, y16, deltab, fcur, ts, was[s4], cys[s4]);
    else
      rk_kernel<0,0><<<ROWS1*DM/256,256,0,stream>>>(accb, nullptr, deltab, fcur, ts, was[s4], 0.f);
    yin16 = y16;
  }
  states_kernel<<<ROWS*DM/256,256,0,stream>>>(x, ts, accb, hin16);

  // ---- GRU ----
  launch_bgemm(0, hin16, wb_gwih, gru_bih, nullptr, gx, nullptr, ROWS, 1536, 512, 1536, stream);
  gru_scan_kernel<<<GRU_BLK, 256, 0, stream>>>(gx, gru_whh, gru_bhh, hsb, hs16, hbuf);

  // ---- time encoding ----
  timeenc_kernel<<<ROWS*DM/256,256,0,stream>>>(x, ts, te_a, te_b, zbuf);

  // ---- transformer (2 layers, pre-norm, causal) ----
  for (int l = 0; l < 2; l++) {
    ln_kernel<1><<<ROWS,256,0,stream>>>(zbuf, t_ln1_w + l*512, t_ln1_b + l*512, ln16);
    launch_bgemm(0, ln16, wb_tin + (size_t)l*1536*512, t_in_b + l*1536, nullptr, nullptr, qkv16, ROWS, 1536, 512, 1536, stream);
    mattn_kernel<1><<<dim3(64, TT/64), 256, 0, stream>>>(qkv16, ao16);
    launch_bgemm(0, ao16, wb_tout + (size_t)l*512*512, t_out_b + l*512, zbuf, zbuf, nullptr, ROWS, 512, 512, 512, stream);
    ln_kernel<1><<<ROWS,256,0,stream>>>(zbuf, t_ln2_w + l*512, t_ln2_b + l*512, ln16);
    launch_bgemm(1, ln16, wb_ff1 + (size_t)l*2048*512, t_ff1_b + l*2048, nullptr, nullptr, ff1b16, ROWS, 2048, 512, 2048, stream);
    launch_bgemm(0, ff1b16, wb_ff2 + (size_t)l*512*2048, t_ff2_b + l*512, zbuf, zbuf, nullptr, ROWS, 512, 2048, 512, stream);
  }
  ln_kernel<1><<<ROWS,256,0,stream>>>(zbuf, t_lnf_w, t_lnf_b, ln16);  // zf bf16

  // ---- cross attention: Q from Hs, K/V from zf ----
  launch_bgemm(0, hs16, wb_cain,           ca_in_b,       nullptr, nullptr, qkv16,       ROWS,  512, 512, 1536, stream);
  launch_bgemm(0, ln16, wb_cain + 512*512, ca_in_b + 512, nullptr, nullptr, qkv16 + 512, ROWS, 1024, 512, 1536, stream);
  mattn_kernel<0><<<dim3(64, TT/64), 256, 0, stream>>>(qkv16, ao16);
  launch_bgemm(0, ao16, wb_caout, ca_out_b, nullptr, nullptr, cao16, ROWS, 512, 512, 512, stream);
  launch_bgemm(0, cao16, wb_calin, ca_lin_b, hsb, fcur, nullptr, ROWS, 512, 512, 512, stream);
  ln_kernel<0><<<ROWS,256,0,stream>>>(fcur, ca_ln_w, ca_ln_b, (float*)d_out);
}

// Round 8
// 2941.103 us; speedup vs baseline: 5.5472x; 1.0871x over previous
//
#include <hip/hip_runtime.h>
#include <math.h>

#define BB 8
#define TT 1024
#define DM 512
#define ROWS (BB*TT)     // 8192
#define ROWS1 (BB*(TT-1))// 8184
#define GRU_J 8
#define GRU_BLK (BB*64)  // 512 blocks

typedef __attribute__((ext_vector_type(4))) float f32x4;
typedef __attribute__((ext_vector_type(8))) short bf16x8;
typedef __attribute__((ext_vector_type(4))) short bf16x4;

struct RkArgs {
  const float* delta; float* acc; unsigned short* y16;
  const float* dtrow; const int* srcrow;
  const float* x; unsigned short* hin16;
  float wa, cy;
};

__device__ __forceinline__ float sigm_(float v){ return 1.f/(1.f+expf(-v)); }

__device__ __forceinline__ unsigned short f2bf(float f){
  unsigned u = __float_as_uint(f);
  return (unsigned short)((u + 0x7FFFu + ((u>>16)&1u)) >> 16);
}

// ---------------- fused weight cast (all 10 weights, 1 launch) ----------------
__global__ __launch_bounds__(256) void castall_kernel(
    const float* w0, const float* w1, const float* w2, const float* w3,
    const float* w4, const float* w5, const float* w6, const float* w7,
    const float* w8, const float* w9, unsigned short* __restrict__ o)
{
  int i = blockIdx.x*256 + threadIdx.x;           // in float4 units
  if (i >= 2228224) return;
  const float* src; int off;
  if      (i <   65536){ src=w0; off=0; }
  else if (i <  131072){ src=w1; off=65536; }
  else if (i <  327680){ src=w2; off=131072; }
  else if (i <  720896){ src=w3; off=327680; }
  else if (i <  851968){ src=w4; off=720896; }
  else if (i < 1376256){ src=w5; off=851968; }
  else if (i < 1900544){ src=w6; off=1376256; }
  else if (i < 2097152){ src=w7; off=1900544; }
  else if (i < 2162688){ src=w8; off=2097152; }
  else                 { src=w9; off=2162688; }
  float4 v = ((const float4*)src)[i - off];
  ushort4 u;
  u.x = f2bf(v.x); u.y = f2bf(v.y); u.z = f2bf(v.z); u.w = f2bf(v.w);
  ((ushort4*)o)[i] = u;
}

// ---------------- elementwise ----------------
__global__ __launch_bounds__(256) void delta_kernel(const float* __restrict__ x,
    const float* __restrict__ ts, float* __restrict__ delta,
    unsigned short* __restrict__ delta16,
    float* __restrict__ dtrow, int* __restrict__ srcrow)
{
  size_t i = (size_t)blockIdx.x*256 + threadIdx.x;
  int d = (int)(i & (DM-1));
  int r = (int)(i >> 9);
  int b = r / (TT-1), ii = r % (TT-1);
  float dt = ts[b*TT+ii+1] - ts[b*TT+ii];
  float x1 = x[((size_t)b*TT+ii+1)*DM + d];
  float x0 = x[((size_t)b*TT+ii)*DM + d];
  float v = (x1 - x0) / dt;
  delta[i] = v;
  delta16[i] = f2bf(v);
  if (d == 0) { dtrow[r] = dt; srcrow[r] = b*TT + ii; }
}

// zero the t=0 rows of H_in. MUST run after the RK chain: hin16 aliases y16,
// and RK y-writes (dense 8184-row indexing) land on rows b*TT for b>=0.
__global__ __launch_bounds__(256) void zero8_kernel(unsigned short* __restrict__ hin16)
{
  int tid = threadIdx.x;
  for (int b = 0; b < BB; b++)
    for (int k = tid; k < DM; k += 256)
      hin16[(size_t)b*TT*DM + k] = 0;
}

__global__ __launch_bounds__(256) void timeenc_kernel(const float* __restrict__ x,
    const float* __restrict__ ts, const float* __restrict__ te_a,
    const float* __restrict__ te_b, float* __restrict__ z)
{
  size_t i = (size_t)blockIdx.x*256 + threadIdx.x;
  int d = (int)(i & (DM-1));
  int r = (int)(i >> 9);
  float t = ts[r];
  float tm;
  if (d & 1) {
    int j = d >> 1;
    tm = t*te_a[j] + te_b[j];
  } else {
    int fi = d >> 2;
    float fr = expf(-(float)fi * 0.061606661f) * 1.5707964f;
    float ph = t * fr;
    tm = ((d & 3) == 0) ? sinf(ph) : cosf(ph);
  }
  z[i] = x[i] + tm;
}

// ---------------- LayerNorm (block per row, D=512) ----------------
template<int BF>
__global__ __launch_bounds__(256) void ln_kernel(const float* __restrict__ x,
    const float* __restrict__ w, const float* __restrict__ b,
    void* __restrict__ outp)
{
  int row = blockIdx.x;
  int tid = threadIdx.x;
  const float* xr = x + (size_t)row*DM;
  float2 v = *(const float2*)(xr + tid*2);
  float s = v.x+v.y, sq = v.x*v.x + v.y*v.y;
  #pragma unroll
  for (int off=1; off<64; off<<=1){ s += __shfl_xor(s,off); sq += __shfl_xor(sq,off); }
  __shared__ float rs[4], rq[4];
  int wid = tid>>6;
  if ((tid&63)==0){ rs[wid]=s; rq[wid]=sq; }
  __syncthreads();
  s = rs[0]+rs[1]+rs[2]+rs[3];
  sq = rq[0]+rq[1]+rq[2]+rq[3];
  float mean = s*(1.f/DM);
  float var = sq*(1.f/DM) - mean*mean;
  float inv = rsqrtf(var + 1e-5f);
  float2 wv = *(const float2*)(w + tid*2);
  float2 bv = *(const float2*)(b + tid*2);
  float ox = (v.x-mean)*inv*wv.x + bv.x;
  float oy = (v.y-mean)*inv*wv.y + bv.y;
  if (BF) {
    ushort2 u; u.x = f2bf(ox); u.y = f2bf(oy);
    *(ushort2*)((unsigned short*)outp + (size_t)row*DM + tid*2) = u;
  } else {
    float2 o; o.x = ox; o.y = oy;
    *(float2*)((float*)outp + (size_t)row*DM + tid*2) = o;
  }
}

// ---------------- bf16 MFMA GEMM ----------------
// TN: 128 (grid N/128) or 64 (grid N/64, 2x blocks for small N -> latency hiding).
// RKM: 0 none, 1 RK-init, 2 RK-mid, 3 RK-final(states) fused epilogues (ldc==512).
template<int ACT, int TN, int RKM>
__global__ __launch_bounds__(256) void bgemm_kernel(
    const unsigned short* __restrict__ A16, const unsigned short* __restrict__ Wb,
    const float* __restrict__ bias, const float* res,
    float* C, unsigned short* Cb, int M, int N, int K, int ldc, RkArgs rk)
{
  const int NJ = TN/32;
  __shared__ __align__(16) unsigned short Al[2][128][40];
  __shared__ __align__(16) unsigned short Wl[2][TN][40];
  const int bm = blockIdx.y*128, bn = blockIdx.x*TN;
  const int tid = threadIdx.x;
  const int lane = tid & 63, wid = tid >> 6;
  const int wm = (wid&1)*64, wn = (wid>>1)*(TN/2);
  const int fl = lane & 15, fk = (lane>>4)*8;
  const int sar = tid>>2, sac = (tid&3)*8;
  f32x4 acc[4][NJ];
  #pragma unroll
  for (int i=0;i<4;i++)
    #pragma unroll
    for (int j=0;j<NJ;j++) acc[i][j] = (f32x4){0.f,0.f,0.f,0.f};

  uint4 areg[2], wreg[TN/64];
  const int nk = K >> 5;

  auto load_t = [&](int kt){
    int k0 = kt*32;
    #pragma unroll
    for (int r=0;r<2;r++){
      int gr = bm + sar + r*64;
      areg[r] = (gr < M) ? *(const uint4*)(A16 + (size_t)gr*K + k0 + sac)
                         : make_uint4(0u,0u,0u,0u);
    }
    #pragma unroll
    for (int r=0;r<TN/64;r++)
      wreg[r] = *(const uint4*)(Wb + (size_t)(bn + sar + r*64)*K + k0 + sac);
  };
  auto store_t = [&](int buf){
    #pragma unroll
    for (int r=0;r<2;r++) *(uint4*)&Al[buf][sar + r*64][sac] = areg[r];
    #pragma unroll
    for (int r=0;r<TN/64;r++) *(uint4*)&Wl[buf][sar + r*64][sac] = wreg[r];
  };

  load_t(0); store_t(0);
  int buf = 0;
  for (int kt = 0; kt < nk; ++kt) {
    __syncthreads();
    if (kt+1 < nk) load_t(kt+1);
    bf16x8 av[4], wv[NJ];
    #pragma unroll
    for (int i=0;i<4;i++) av[i] = *(const bf16x8*)&Al[buf][wm + i*16 + fl][fk];
    #pragma unroll
    for (int j=0;j<NJ;j++) wv[j] = *(const bf16x8*)&Wl[buf][wn + j*16 + fl][fk];
    #pragma unroll
    for (int i=0;i<4;i++)
      #pragma unroll
      for (int j=0;j<NJ;j++)
        acc[i][j] = __builtin_amdgcn_mfma_f32_16x16x32_bf16(av[i], wv[j], acc[i][j], 0, 0, 0);
    if (kt+1 < nk) store_t(buf^1);
    buf ^= 1;
  }

  // epilogue: C/D layout col=lane&15, row=(lane>>4)*4+reg
  #pragma unroll
  for (int j=0;j<NJ;j++){
    int gn = bn + wn + j*16 + fl;
    float bv = bias[gn];
    #pragma unroll
    for (int i=0;i<4;i++){
      #pragma unroll
      for (int r=0;r<4;r++){
        int gm = bm + wm + i*16 + (lane>>4)*4 + r;
        if (gm >= M) continue;
        float v = acc[i][j][r] + bv;
        if (ACT==1) v = fmaxf(v, 0.f);
        if (ACT==2) v = tanhf(v);
        if (RKM == 0) {
          if (res) v += res[(size_t)gm*ldc + gn];
          if (C)  C[(size_t)gm*ldc + gn] = v;
          if (Cb) Cb[(size_t)gm*ldc + gn] = f2bf(v);
        } else {
          size_t idx = (size_t)gm*512 + gn;
          float dt = rk.dtrow[gm];
          if (RKM == 1) {
            rk.acc[idx] = v;
            rk.y16[idx] = f2bf(rk.delta[idx] + rk.cy*dt*v);
          } else if (RKM == 2) {
            rk.acc[idx] += rk.wa*v;
            rk.y16[idx] = f2bf(rk.delta[idx] + rk.cy*dt*v);
          } else {
            float a = rk.acc[idx] + v;
            int srow = rk.srcrow[gm];
            rk.hin16[((size_t)srow+1)*512 + gn] =
                f2bf(rk.x[(size_t)srow*512 + gn] + dt*(1.f/6.f)*a);
          }
        }
      }
    }
  }
}

// ---------------- MFMA flash attention ----------------
template<int CAUSAL>
__global__ __launch_bounds__(256) void mattn_kernel(
    const unsigned short* __restrict__ QKV, unsigned short* __restrict__ O)
{
  __shared__ __align__(16) unsigned short Kl[32][72];
  __shared__ __align__(16) unsigned short Vt[64][36];
  __shared__ __align__(16) unsigned short Pl[4][16][40];
  const int b = blockIdx.x >> 3, h = blockIdx.x & 7;
  const int q0 = blockIdx.y * 64;
  const int tid = threadIdx.x;
  const int lane = tid & 63, wid = tid >> 6;
  const int lq = lane & 15, g = lane >> 4;
  const size_t rowbase = (size_t)b*TT;

  bf16x8 qf0, qf1;
  {
    const unsigned short* qp = QKV + (rowbase + q0 + wid*16 + lq)*1536 + h*64 + g*8;
    qf0 = *(const bf16x8*)qp;
    qf1 = *(const bf16x8*)(qp + 32);
  }
  f32x4 o[4];
  #pragma unroll
  for (int dt=0; dt<4; dt++) o[dt] = (f32x4){0.f,0.f,0.f,0.f};
  float mr[4] = {-1e30f,-1e30f,-1e30f,-1e30f};
  float Lr[4] = {0.f,0.f,0.f,0.f};

  const int nkt = CAUSAL ? (q0/32 + 2) : (TT/32);
  const int qwmax = q0 + wid*16 + 15;
  const int sr = tid >> 3, scol = (tid & 7) * 8;

  for (int kt = 0; kt < nkt; ++kt) {
    const int k0 = kt*32;
    __syncthreads();
    *(uint4*)&Kl[sr][scol] = *(const uint4*)(QKV + (rowbase + k0 + sr)*1536 + 512 + h*64 + scol);
    {
      uint4 vv = *(const uint4*)(QKV + (rowbase + k0 + sr)*1536 + 1024 + h*64 + scol);
      const unsigned short* vs = (const unsigned short*)&vv;
      #pragma unroll
      for (int i=0;i<8;i++) Vt[scol+i][sr] = vs[i];
    }
    __syncthreads();
    if (CAUSAL && k0 > qwmax) continue;

    f32x4 st0 = (f32x4){0.f,0.f,0.f,0.f}, st1 = (f32x4){0.f,0.f,0.f,0.f};
    {
      bf16x8 kb;
      kb = *(const bf16x8*)&Kl[lq][g*8];
      st0 = __builtin_amdgcn_mfma_f32_16x16x32_bf16(qf0, kb, st0, 0,0,0);
      kb = *(const bf16x8*)&Kl[lq][g*8+32];
      st0 = __builtin_amdgcn_mfma_f32_16x16x32_bf16(qf1, kb, st0, 0,0,0);
      kb = *(const bf16x8*)&Kl[16+lq][g*8];
      st1 = __builtin_amdgcn_mfma_f32_16x16x32_bf16(qf0, kb, st1, 0,0,0);
      kb = *(const bf16x8*)&Kl[16+lq][g*8+32];
      st1 = __builtin_amdgcn_mfma_f32_16x16x32_bf16(qf1, kb, st1, 0,0,0);
    }
    float s0[4], s1[4];
    #pragma unroll
    for (int r=0;r<4;r++){ s0[r] = st0[r]*0.125f; s1[r] = st1[r]*0.125f; }
    if (CAUSAL) {
      int kg0 = k0 + lq, kg1 = k0 + 16 + lq;
      #pragma unroll
      for (int r=0;r<4;r++){
        int qg = q0 + wid*16 + 4*g + r;
        if (kg0 > qg) s0[r] = -1e30f;
        if (kg1 > qg) s1[r] = -1e30f;
      }
    }
    #pragma unroll
    for (int r=0;r<4;r++){
      float v = fmaxf(s0[r], s1[r]);
      v = fmaxf(v, __shfl_xor(v,1));
      v = fmaxf(v, __shfl_xor(v,2));
      v = fmaxf(v, __shfl_xor(v,4));
      v = fmaxf(v, __shfl_xor(v,8));
      float mn = fmaxf(mr[r], v);
      float scl = expf(mr[r] - mn);
      mr[r] = mn;
      float p0 = expf(s0[r] - mn);
      float p1 = expf(s1[r] - mn);
      float lt = p0 + p1;
      lt += __shfl_xor(lt,1); lt += __shfl_xor(lt,2);
      lt += __shfl_xor(lt,4); lt += __shfl_xor(lt,8);
      Lr[r] = Lr[r]*scl + lt;
      o[0][r] *= scl; o[1][r] *= scl; o[2][r] *= scl; o[3][r] *= scl;
      Pl[wid][4*g+r][lq]    = f2bf(p0);
      Pl[wid][4*g+r][16+lq] = f2bf(p1);
    }
    bf16x8 ap = *(const bf16x8*)&Pl[wid][lq][g*8];
    #pragma unroll
    for (int dt=0; dt<4; dt++){
      bf16x4 a4 = *(const bf16x4*)&Vt[lq+16*dt][g*8];
      bf16x4 b4 = *(const bf16x4*)&Vt[lq+16*dt][g*8+4];
      bf16x8 vb = __builtin_shufflevector(a4, b4, 0,1,2,3,4,5,6,7);
      o[dt] = __builtin_amdgcn_mfma_f32_16x16x32_bf16(ap, vb, o[dt], 0,0,0);
    }
  }

  #pragma unroll
  for (int r=0;r<4;r++){
    float inv = 1.f / Lr[r];
    int qg = q0 + wid*16 + 4*g + r;
    unsigned short* op = O + (rowbase + qg)*DM + h*64 + lq;
    op[0]  = f2bf(o[0][r]*inv);
    op[16] = f2bf(o[1][r]*inv);
    op[32] = f2bf(o[2][r]*inv);
    op[48] = f2bf(o[3][r]*inv);
  }
}

// ---------------- GRU scan v4.1: tagged-value sync ----------------
__global__ __launch_bounds__(256) void gru_scan_kernel(
    const float* __restrict__ gx,
    const float* __restrict__ whh,
    const float* __restrict__ bhh,
    float* __restrict__ Hs,
    unsigned short* __restrict__ Hsb,
    unsigned long long* hbuf)
{
  __shared__ float wlds[3][GRU_J][512];
  __shared__ float hsp[512];
  const int blk = blockIdx.x;
  const int b = blk & 7;
  const int g = blk >> 3;
  const int j0 = g * GRU_J;
  const int tid = threadIdx.x;

  for (int idx = tid; idx < 3*GRU_J*512/4; idx += 256) {
    int f = idx*4;
    int gate = f >> 12;
    int rem = f & 4095;
    int jj = rem >> 9, k = rem & 511;
    *(float4*)&wlds[gate][jj][k] = *(const float4*)&whh[(size_t)(gate*512 + j0 + jj)*512 + k];
  }
  const int row = tid >> 5;
  const int kl = tid & 31;
  const bool fin = (kl == 0);
  float bh0=0.f, bh1=0.f, bh2=0.f;
  if (fin) { bh0 = bhh[j0+row]; bh1 = bhh[512+j0+row]; bh2 = bhh[1024+j0+row]; }
  __syncthreads();

  for (int t = 0; t < TT; t++) {
    float g0=0.f, g1=0.f, g2=0.f;
    if (fin) {
      const float* gxr = gx + ((size_t)b*TT + t)*1536 + j0 + row;
      g0 = gxr[0]; g1 = gxr[512]; g2 = gxr[1024];
    }
    if (t == 0) {
      hsp[tid] = 0.f; hsp[tid+256] = 0.f;
    } else {
      const unsigned want = (unsigned)t;
      unsigned long long* src = hbuf + ((size_t)((t-1)&1)*BB + b)*512;
      unsigned long long u0, u1;
      for (;;) {
        u0 = __hip_atomic_load(src + tid,       __ATOMIC_RELAXED, __HIP_MEMORY_SCOPE_AGENT);
        u1 = __hip_atomic_load(src + tid + 256, __ATOMIC_RELAXED, __HIP_MEMORY_SCOPE_AGENT);
        if (((unsigned)(u0>>32) == want) & ((unsigned)(u1>>32) == want)) break;
        __builtin_amdgcn_s_sleep(1);
      }
      hsp[tid]     = __uint_as_float((unsigned)u0);
      hsp[tid+256] = __uint_as_float((unsigned)u1);
    }
    __syncthreads();

    float s0=0.f, s1=0.f, s2=0.f;
    #pragma unroll
    for (int j=0;j<4;j++){
      int k = kl*4 + j*128;
      float4 h4 = *(const float4*)&hsp[k];
      float4 a = *(const float4*)&wlds[0][row][k];
      float4 c = *(const float4*)&wlds[1][row][k];
      float4 d = *(const float4*)&wlds[2][row][k];
      s0 += a.x*h4.x + a.y*h4.y + a.z*h4.z + a.w*h4.w;
      s1 += c.x*h4.x + c.y*h4.y + c.z*h4.z + c.w*h4.w;
      s2 += d.x*h4.x + d.y*h4.y + d.z*h4.z + d.w*h4.w;
    }
    #pragma unroll
    for (int off=1; off<32; off<<=1) {
      s0 += __shfl_xor(s0, off);
      s1 += __shfl_xor(s1, off);
      s2 += __shfl_xor(s2, off);
    }
    if (fin) {
      float r  = sigm_(g0 + s0 + bh0);
      float z  = sigm_(g1 + s1 + bh1);
      float n  = tanhf(g2 + r*(s2 + bh2));
      float hold = hsp[j0 + row];
      float hnew = (1.f - z)*n + z*hold;
      size_t off = ((size_t)b*TT + t)*DM + j0 + row;
      Hs[off]  = hnew;
      Hsb[off] = f2bf(hnew);
      unsigned long long pk = ((unsigned long long)(unsigned)(t+1) << 32) | __float_as_uint(hnew);
      __hip_atomic_store(&hbuf[((size_t)(t&1)*BB + b)*512 + j0 + row], pk,
                         __ATOMIC_RELAXED, __HIP_MEMORY_SCOPE_AGENT);
    }
    __syncthreads();
  }
}

// ---------------- host ----------------
static RkArgs g_norm = {};

static void launch_bgemm(int act, int tn, const unsigned short* A16, const unsigned short* Wb,
                         const float* bias, const float* res, float* C, unsigned short* Cb,
                         int M, int N, int K, int ldc, hipStream_t stream)
{
  dim3 blk(256);
  if (tn == 128) {
    dim3 grid(N/128, (M+127)/128);
    switch(act){
      case 1: bgemm_kernel<1,128,0><<<grid,blk,0,stream>>>(A16,Wb,bias,res,C,Cb,M,N,K,ldc,g_norm); break;
      default: bgemm_kernel<0,128,0><<<grid,blk,0,stream>>>(A16,Wb,bias,res,C,Cb,M,N,K,ldc,g_norm); break;
    }
  } else {
    dim3 grid(N/64, (M+127)/128);
    switch(act){
      case 2: bgemm_kernel<2,64,0><<<grid,blk,0,stream>>>(A16,Wb,bias,res,C,Cb,M,N,K,ldc,g_norm); break;
      default: bgemm_kernel<0,64,0><<<grid,blk,0,stream>>>(A16,Wb,bias,res,C,Cb,M,N,K,ldc,g_norm); break;
    }
  }
}

extern "C" void kernel_launch(void* const* d_in, const int* in_sizes, int n_in,
                              void* d_out, int out_size, void* d_ws, size_t ws_size,
                              hipStream_t stream)
{
  (void)in_sizes; (void)n_in; (void)out_size; (void)ws_size;
  const float* x       = (const float*)d_in[0];
  const float* ts      = (const float*)d_in[1];
  const float* ode_w1  = (const float*)d_in[2];
  const float* ode_b1  = (const float*)d_in[3];
  const float* ode_w2  = (const float*)d_in[4];
  const float* ode_b2  = (const float*)d_in[5];
  const float* gru_wih = (const float*)d_in[6];
  const float* gru_whh = (const float*)d_in[7];
  const float* gru_bih = (const float*)d_in[8];
  const float* gru_bhh = (const float*)d_in[9];
  const float* te_a    = (const float*)d_in[10];
  const float* te_b    = (const float*)d_in[11];
  const float* t_in_w  = (const float*)d_in[12];
  const float* t_in_b  = (const float*)d_in[13];
  const float* t_out_w = (const float*)d_in[14];
  const float* t_out_b = (const float*)d_in[15];
  const float* t_ln1_w = (const float*)d_in[16];
  const float* t_ln1_b = (const float*)d_in[17];
  const float* t_ln2_w = (const float*)d_in[18];
  const float* t_ln2_b = (const float*)d_in[19];
  const float* t_ff1_w = (const float*)d_in[20];
  const float* t_ff1_b = (const float*)d_in[21];
  const float* t_ff2_w = (const float*)d_in[22];
  const float* t_ff2_b = (const float*)d_in[23];
  const float* t_lnf_w = (const float*)d_in[24];
  const float* t_lnf_b = (const float*)d_in[25];
  const float* ca_in_w = (const float*)d_in[26];
  const float* ca_in_b = (const float*)d_in[27];
  const float* ca_out_w= (const float*)d_in[28];
  const float* ca_out_b= (const float*)d_in[29];
  const float* ca_lin_w= (const float*)d_in[30];
  const float* ca_lin_b= (const float*)d_in[31];
  const float* ca_ln_w = (const float*)d_in[32];
  const float* ca_ln_b = (const float*)d_in[33];

  float* ws = (float*)d_ws;
  const size_t SZ = (size_t)ROWS * DM;
  // f32 pool
  float* deltab = ws + 0*SZ;
  float* accb   = ws + 1*SZ;
  float* fcur   = ws + 2*SZ;                 // ca pre-LN
  float* gx     = ws + 3*SZ;                 // 3*SZ
  float* zbuf   = ws + 6*SZ;
  float* hsb    = ws + 7*SZ;
  unsigned long long* hbuf = (unsigned long long*)(ws + 8*SZ);   // 64KB
  float* dtrow  = ws + 8*SZ + 16384;                              // 8184 f32
  int*   srcrow = (int*)(ws + 8*SZ + 16384 + 8192);               // 8184 i32
  // bf16 pool
  unsigned short* u16 = (unsigned short*)(ws + 8*SZ + 16384 + 16384);
  unsigned short* delta16 = u16 + 0*SZ;
  unsigned short* y16     = u16 + 1*SZ;
  unsigned short* t16     = u16 + 2*SZ;
  unsigned short* hs16    = u16 + 3*SZ;
  unsigned short* ff1b16  = u16 + 4*SZ;      // 4*SZ; qkv16 aliases
  unsigned short* qkv16   = ff1b16;
  unsigned short* ao16    = delta16;
  unsigned short* hin16   = y16;
  unsigned short* cao16   = y16;
  unsigned short* ln16    = t16;
  // weights (one fused cast; offsets match castall table, in elems = 4*n4off)
  unsigned short* wb = u16 + 8*SZ;
  unsigned short* wb_ode1 = wb + 0;
  unsigned short* wb_ode2 = wb + 262144;
  unsigned short* wb_gwih = wb + 524288;
  unsigned short* wb_tin  = wb + 1310720;
  unsigned short* wb_tout = wb + 2883584;
  unsigned short* wb_ff1  = wb + 3407872;
  unsigned short* wb_ff2  = wb + 5505024;
  unsigned short* wb_cain = wb + 7602176;
  unsigned short* wb_caout= wb + 8388608;
  unsigned short* wb_calin= wb + 8650752;

  castall_kernel<<<(2228224+255)/256, 256, 0, stream>>>(
      ode_w1, ode_w2, gru_wih, t_in_w, t_out_w, t_ff1_w, t_ff2_w,
      ca_in_w, ca_out_w, ca_lin_w, wb);

  // ---- ODE (RK4), rk+states fused into ode2 epilogues ----
  delta_kernel<<<ROWS1*DM/256, 256, 0, stream>>>(x, ts, deltab, delta16, dtrow, srcrow);
  RkArgs rk; rk.delta = deltab; rk.acc = accb; rk.y16 = y16;
  rk.dtrow = dtrow; rk.srcrow = srcrow; rk.x = x; rk.hin16 = hin16;
  const unsigned short* yin16 = delta16;
  const float was[4] = {1.f, 2.f, 2.f, 1.f};
  const float cys[4] = {0.5f, 0.5f, 1.f, 0.f};
  for (int s4 = 0; s4 < 4; s4++) {
    launch_bgemm(2, 64, yin16, wb_ode1, ode_b1, nullptr, nullptr, t16, ROWS1, 512, 512, 512, stream);
    rk.wa = was[s4]; rk.cy = cys[s4];
    dim3 grid(512/64, (ROWS1+127)/128), blk(256);
    if (s4 == 0)
      bgemm_kernel<0,64,1><<<grid,blk,0,stream>>>(t16, wb_ode2, ode_b2, nullptr, nullptr, nullptr, ROWS1, 512, 512, 512, rk);
    else if (s4 < 3)
      bgemm_kernel<0,64,2><<<grid,blk,0,stream>>>(t16, wb_ode2, ode_b2, nullptr, nullptr, nullptr, ROWS1, 512, 512, 512, rk);
    else
      bgemm_kernel<0,64,3><<<grid,blk,0,stream>>>(t16, wb_ode2, ode_b2, nullptr, nullptr, nullptr, ROWS1, 512, 512, 512, rk);
    yin16 = y16;
  }
  // zero t=0 rows AFTER the RK chain (hin16 aliases y16 — R7 bug was zeroing first)
  zero8_kernel<<<1, 256, 0, stream>>>(hin16);

  // ---- GRU ----
  launch_bgemm(0, 128, hin16, wb_gwih, gru_bih, nullptr, gx, nullptr, ROWS, 1536, 512, 1536, stream);
  gru_scan_kernel<<<GRU_BLK, 256, 0, stream>>>(gx, gru_whh, gru_bhh, hsb, hs16, hbuf);

  // ---- time encoding ----
  timeenc_kernel<<<ROWS*DM/256,256,0,stream>>>(x, ts, te_a, te_b, zbuf);

  // ---- transformer (2 layers, pre-norm, causal) ----
  for (int l = 0; l < 2; l++) {
    ln_kernel<1><<<ROWS,256,0,stream>>>(zbuf, t_ln1_w + l*512, t_ln1_b + l*512, ln16);
    launch_bgemm(0, 128, ln16, wb_tin + (size_t)l*1536*512, t_in_b + l*1536, nullptr, nullptr, qkv16, ROWS, 1536, 512, 1536, stream);
    mattn_kernel<1><<<dim3(64, TT/64), 256, 0, stream>>>(qkv16, ao16);
    launch_bgemm(0, 64, ao16, wb_tout + (size_t)l*512*512, t_out_b + l*512, zbuf, zbuf, nullptr, ROWS, 512, 512, 512, stream);
    ln_kernel<1><<<ROWS,256,0,stream>>>(zbuf, t_ln2_w + l*512, t_ln2_b + l*512, ln16);
    launch_bgemm(1, 128, ln16, wb_ff1 + (size_t)l*2048*512, t_ff1_b + l*2048, nullptr, nullptr, ff1b16, ROWS, 2048, 512, 2048, stream);
    launch_bgemm(0, 64, ff1b16, wb_ff2 + (size_t)l*512*2048, t_ff2_b + l*512, zbuf, zbuf, nullptr, ROWS, 512, 2048, 512, stream);
  }
  ln_kernel<1><<<ROWS,256,0,stream>>>(zbuf, t_lnf_w, t_lnf_b, ln16);

  // ---- cross attention ----
  launch_bgemm(0, 64,  hs16, wb_cain,           ca_in_b,       nullptr, nullptr, qkv16,       ROWS,  512, 512, 1536, stream);
  launch_bgemm(0, 128, ln16, wb_cain + 512*512, ca_in_b + 512, nullptr, nullptr, qkv16 + 512, ROWS, 1024, 512, 1536, stream);
  mattn_kernel<0><<<dim3(64, TT/64), 256, 0, stream>>>(qkv16, ao16);
  launch_bgemm(0, 64, ao16, wb_caout, ca_out_b, nullptr, nullptr, cao16, ROWS, 512, 512, 512, stream);
  launch_bgemm(0, 64, cao16, wb_calin, ca_lin_b, hsb, fcur, nullptr, ROWS, 512, 512, 512, stream);
  ln_kernel<0><<<ROWS,256,0,stream>>>(fcur, ca_ln_w, ca_ln_b, (float*)d_out);
}